// Round 1
// baseline (1240.110 us; speedup 1.0000x reference)
//
#include <hip/hip_runtime.h>
#include <cstdint>

// ---- JAX PRNG mode: 1 = jax_threefry_partitionable (default since JAX 0.4.30)
#define JAX_PARTITIONABLE 1

#define B_ 512
#define N_ 150
#define NT 640
#define STR 151            // padded LDS row stride (odd -> <=2-way bank alias)
#define C1f 144.26950408889634f    // log2(e)/eps, eps=0.01
#define C0f -7.2288186904958804f   // -log2(150) == log2(e)*log(1/N)
#define LN2f 0.69314718055994531f
#define SIGMAf 1.0e-4f

// Threefry-2x32, 20 rounds, exactly as JAX's threefry2x32 lowering.
__host__ __device__ __forceinline__ void tf2x32(uint32_t k0, uint32_t k1,
                                                uint32_t x0, uint32_t x1,
                                                uint32_t& o0, uint32_t& o1) {
  uint32_t ks2 = k0 ^ k1 ^ 0x1BD11BDAu;
  x0 += k0; x1 += k1;
#define TFR(r) { x0 += x1; x1 = (x1 << r) | (x1 >> (32 - r)); x1 ^= x0; }
  TFR(13) TFR(15) TFR(26) TFR(6)
  x0 += k1;  x1 += ks2 + 1u;
  TFR(17) TFR(29) TFR(16) TFR(24)
  x0 += ks2; x1 += k0 + 2u;
  TFR(13) TFR(15) TFR(26) TFR(6)
  x0 += k0;  x1 += k1 + 3u;
  TFR(17) TFR(29) TFR(16) TFR(24)
  x0 += k1;  x1 += ks2 + 4u;
  TFR(13) TFR(15) TFR(26) TFR(6)
  x0 += ks2; x1 += k0 + 5u;
#undef TFR
  o0 = x0; o1 = x1;
}

// _random_bits(key, 32, shape)[p]; half = prod(shape)/2 (legacy mode only).
__device__ __forceinline__ uint32_t jax_bits(uint32_t k0, uint32_t k1,
                                             uint32_t p, uint32_t half) {
#if JAX_PARTITIONABLE
  (void)half;
  uint32_t a, b; tf2x32(k0, k1, 0u, p, a, b);   // counter = (hi=0, lo=p)
  return a ^ b;
#else
  uint32_t a, b;
  if (p < half) { tf2x32(k0, k1, p, p + half, a, b); return a; }
  tf2x32(k0, k1, p - half, p, a, b); return b;
#endif
}

__global__ __launch_bounds__(NT) void cfm_ot_kernel(
    const float* __restrict__ x1g, const float* __restrict__ maskg,
    const float* __restrict__ tg, const float* __restrict__ x0g,
    const float* __restrict__ epsg,
    const float* __restrict__ W1, const float* __restrict__ b1,
    const float* __restrict__ W2, const float* __restrict__ b2,
    float* __restrict__ partials,
    uint32_t kj0, uint32_t kj1, uint32_t k1r0, uint32_t k1r1,
    uint32_t k2r0, uint32_t k2r1)
{
  extern __shared__ float sm[];
  float* Mn  = sm;                 // [N_*STR]  -M[i,j]*log2(e)/eps
  float* x1L = Mn + N_ * STR;      // [450]
  float* x0L = x1L + 450;          // [450]
  float* phi = x0L + 450;          // [150]  f*log2(e)/eps
  float* psi = phi + N_;           // [150]  g*log2(e)/eps
  float* red = psi + N_;           // [16]

  const int b    = blockIdx.x;
  const int tid  = threadIdx.x;
  const int lane = tid & 63;
  const int wid  = tid >> 6;
  const int col  = tid >> 2;   // column (or row in the phi update)
  const int h    = tid & 3;    // quad slot: 38-element segment

  if (tid < 450) {
    x1L[tid] = x1g[b * 450 + tid];
    x0L[tid] = x0g[b * 450 + tid];
  }
  if (tid < N_) { phi[tid] = 0.f; psi[tid] = 0.f; }
  __syncthreads();

  // ---- squared distances D[i][j], track block max ----
  float lmax = 0.f;
  if (col < N_) {
    const float a0 = x1L[col * 3 + 0], a1 = x1L[col * 3 + 1], a2 = x1L[col * 3 + 2];
    #pragma unroll
    for (int k = 0; k < 38; ++k) {
      const int i = 38 * h + k;
      if (i < N_) {
        const float dx = x0L[i * 3 + 0] - a0;
        const float dy = x0L[i * 3 + 1] - a1;
        const float dz = x0L[i * 3 + 2] - a2;
        const float d = fmaf(dz, dz, fmaf(dy, dy, dx * dx));
        Mn[i * STR + col] = d;
        lmax = fmaxf(lmax, d);
      }
    }
  }
  #pragma unroll
  for (int off = 1; off < 64; off <<= 1) lmax = fmaxf(lmax, __shfl_xor(lmax, off));
  if (lane == 0) red[wid] = lmax;
  __syncthreads();
  if (tid == 0) {
    float m = red[0];
    #pragma unroll
    for (int w = 1; w < 10; ++w) m = fmaxf(m, red[w]);
    red[15] = -C1f / m;          // negative scale: Mn := -D * log2(e)/(eps*maxD)
  }
  __syncthreads();
  const float nsc = red[15];
  if (col < N_) {
    #pragma unroll
    for (int k = 0; k < 38; ++k) {
      const int i = 38 * h + k;
      if (i < N_) Mn[i * STR + col] *= nsc;
    }
  }
  __syncthreads();

  // ---- 100 Sinkhorn iterations, log2 domain ----
  for (int it = 0; it < 100; ++it) {
    // psi (g) update: LSE over i for each column j=col
    if (col < N_) {
      float c[38]; float m = -1e30f;
      #pragma unroll
      for (int k = 0; k < 38; ++k) {
        const int i = 38 * h + k;
        if (i < N_) { const float v = phi[i] + Mn[i * STR + col]; c[k] = v; m = fmaxf(m, v); }
        else c[k] = -1e30f;
      }
      m = fmaxf(m, __shfl_xor(m, 1));
      m = fmaxf(m, __shfl_xor(m, 2));
      float s = 0.f;
      #pragma unroll
      for (int k = 0; k < 38; ++k) s += exp2f(c[k] - m);
      s += __shfl_xor(s, 1);
      s += __shfl_xor(s, 2);
      if (h == 0) psi[col] = C0f - (m + log2f(s));
    }
    __syncthreads();
    // phi (f) update: LSE over j for each row i=col
    if (col < N_) {
      float c[38]; float m = -1e30f;
      #pragma unroll
      for (int k = 0; k < 38; ++k) {
        const int j = 38 * h + k;
        if (j < N_) { const float v = psi[j] + Mn[col * STR + j]; c[k] = v; m = fmaxf(m, v); }
        else c[k] = -1e30f;
      }
      m = fmaxf(m, __shfl_xor(m, 1));
      m = fmaxf(m, __shfl_xor(m, 2));
      float s = 0.f;
      #pragma unroll
      for (int k = 0; k < 38; ++k) s += exp2f(c[k] - m);
      s += __shfl_xor(s, 1);
      s += __shfl_xor(s, 2);
      if (h == 0) phi[col] = C0f - (m + log2f(s));
    }
    __syncthreads();
  }

  // ---- sampling + MLP + loss: one wave per sample n ----
  const float tb = tg[b];
  float wacc = 0.f;
  for (int n = wid; n < N_; n += 10) {
    const uint32_t p = (uint32_t)(b * N_ + n);
    // i = randint(ki,(B,N),0,150): (hi%150)*(2^32%150) + lo%150, mod 150
    const uint32_t hb = jax_bits(k1r0, k1r1, p, 38400u);
    const uint32_t lb = jax_bits(k2r0, k2r1, p, 38400u);
    const int isel = (int)(((hb % 150u) * 46u + (lb % 150u)) % 150u);
    const float phi_i = phi[isel];
    const float* MnRow = Mn + isel * STR;

    // j = argmax_k( gumbel + (f_i + g_k - M_ik)/eps ), first index on tie
    float best = -1e30f; int bestk = 0x7fffffff;
    #pragma unroll
    for (int c2 = 0; c2 < 3; ++c2) {
      const int k = lane + 64 * c2;
      if (k < N_) {
        const uint32_t bits = jax_bits(kj0, kj1, p * 150u + (uint32_t)k, 5760000u);
        float u = __uint_as_float((bits >> 9) | 0x3F800000u) - 1.0f;
        u = fmaxf(u, 1.17549435e-38f);
        const float g = -logf(-logf(u));
        const float val = fmaf(phi_i + psi[k] + MnRow[k], LN2f, g);
        if (val > best || (val == best && k < bestk)) { best = val; bestk = k; }
      }
    }
    #pragma unroll
    for (int off = 1; off < 64; off <<= 1) {
      const float ov = __shfl_xor(best, off);
      const int   ok = __shfl_xor(bestk, off);
      if (ov > best || (ov == best && ok < bestk)) { best = ov; bestk = ok; }
    }
    const int j = bestk;

    const float mot = maskg[b * N_ + j];
    const float p0 = x0L[isel * 3 + 0], p1 = x0L[isel * 3 + 1], p2 = x0L[isel * 3 + 2];
    const float q0 = x1L[j * 3 + 0],    q1 = x1L[j * 3 + 1],    q2 = x1L[j * 3 + 2];
    const float omt = 1.f - tb;
    const float y0 = p0 * tb + q0 * omt + SIGMAf * epsg[b * 450 + n * 3 + 0];
    const float y1 = p1 * tb + q1 * omt + SIGMAf * epsg[b * 450 + n * 3 + 1];
    const float y2 = p2 * tb + q2 * omt + SIGMAf * epsg[b * 450 + n * 3 + 2];
    const float u0 = (p0 - q0) * mot, u1 = (p1 - q1) * mot, u2 = (p2 - q2) * mot;

    float a0 = 0.f, a1 = 0.f, a2 = 0.f;
    #pragma unroll
    for (int qq = 0; qq < 8; ++qq) {
      const int hd = 64 * qq + lane;
      float z = b1[hd];
      z = fmaf(y0, W1[hd],        z);
      z = fmaf(y1, W1[512 + hd],  z);
      z = fmaf(y2, W1[1024 + hd], z);
      z = fmaf(tb, W1[1536 + hd], z);
      const float zc = fmaf(0.044715f * z, z * z, z);   // z + 0.044715 z^3
      const float th = tanhf(0.7978845608028654f * zc);
      const float ge = 0.5f * z * (1.f + th);
      a0 = fmaf(ge, W2[hd * 3 + 0], a0);
      a1 = fmaf(ge, W2[hd * 3 + 1], a1);
      a2 = fmaf(ge, W2[hd * 3 + 2], a2);
    }
    #pragma unroll
    for (int off = 1; off < 64; off <<= 1) {
      a0 += __shfl_xor(a0, off);
      a1 += __shfl_xor(a1, off);
      a2 += __shfl_xor(a2, off);
    }
    const float v0 = (a0 + b2[0]) * mot;
    const float v1 = (a1 + b2[1]) * mot;
    const float v2 = (a2 + b2[2]) * mot;
    const float d0 = v0 - u0, d1 = v1 - u1, d2 = v2 - u2;
    wacc += fmaf(d2, d2, fmaf(d1, d1, d0 * d0));
  }

  if (lane == 0) red[wid] = wacc;
  __syncthreads();
  if (tid == 0) {
    float s = 0.f;
    #pragma unroll
    for (int w = 0; w < 10; ++w) s += red[w];
    partials[b] = s;
  }
}

__global__ void cfm_reduce_kernel(const float* __restrict__ partials,
                                  float* __restrict__ out) {
  const int tid = threadIdx.x;   // 64 threads
  float s = 0.f;
  #pragma unroll
  for (int q = 0; q < 8; ++q) s += partials[tid + 64 * q];
  #pragma unroll
  for (int off = 1; off < 64; off <<= 1) s += __shfl_xor(s, off);
  if (tid == 0) out[0] = s * (1.0f / 230400.0f);   // mean over B*N*F
}

extern "C" void kernel_launch(void* const* d_in, const int* in_sizes, int n_in,
                              void* d_out, int out_size, void* d_ws, size_t ws_size,
                              hipStream_t stream) {
  (void)in_sizes; (void)n_in; (void)out_size; (void)ws_size;
  const float* x    = (const float*)d_in[0];   // x1
  const float* mask = (const float*)d_in[1];
  const float* t    = (const float*)d_in[2];
  const float* x0n  = (const float*)d_in[3];   // x0
  const float* epsn = (const float*)d_in[4];
  const float* W1   = (const float*)d_in[5];
  const float* b1   = (const float*)d_in[6];
  const float* W2   = (const float*)d_in[7];
  const float* b2   = (const float*)d_in[8];
  float* out = (float*)d_out;
  float* partials = (float*)d_ws;              // 512 floats

  // Host-side key derivation: key(42) -> split -> (ki,kj); randint splits ki.
  uint32_t ki0, ki1, kj0, kj1, k1r0, k1r1, k2r0, k2r1;
#if JAX_PARTITIONABLE
  tf2x32(0u, 42u, 0u, 0u, ki0, ki1);
  tf2x32(0u, 42u, 0u, 1u, kj0, kj1);
  tf2x32(ki0, ki1, 0u, 0u, k1r0, k1r1);
  tf2x32(ki0, ki1, 0u, 1u, k2r0, k2r1);
#else
  uint32_t e0, e1, f0, f1;
  tf2x32(0u, 42u, 0u, 2u, e0, e1);
  tf2x32(0u, 42u, 1u, 3u, f0, f1);
  ki0 = e0; ki1 = f0; kj0 = e1; kj1 = f1;
  tf2x32(ki0, ki1, 0u, 2u, e0, e1);
  tf2x32(ki0, ki1, 1u, 3u, f0, f1);
  k1r0 = e0; k1r1 = f0; k2r0 = e1; k2r1 = f1;
#endif

  const int SMEM = (N_ * STR + 450 + 450 + N_ + N_ + 16) * (int)sizeof(float);
  (void)hipFuncSetAttribute(reinterpret_cast<const void*>(cfm_ot_kernel),
                            hipFuncAttributeMaxDynamicSharedMemorySize, SMEM);
  cfm_ot_kernel<<<512, NT, SMEM, stream>>>(x, mask, t, x0n, epsn, W1, b1, W2, b2,
                                           partials, kj0, kj1, k1r0, k1r1, k2r0, k2r1);
  cfm_reduce_kernel<<<1, 64, 0, stream>>>(partials, out);
}

// Round 2
// 1133.386 us; speedup vs baseline: 1.0942x; 1.0942x over previous
//
#include <hip/hip_runtime.h>
#include <cstdint>

// ---- JAX PRNG mode: 1 = jax_threefry_partitionable (default since JAX 0.4.30)
#define JAX_PARTITIONABLE 1

#define B_ 512
#define N_ 150
#define NT 640
#define RPAD 160           // padded rows of Mn
#define STR2 152           // padded cols (16B-aligned rows: 152*4B = 38 float4)
#define C1f 144.26950408889634f    // log2(e)/eps, eps=0.01
#define C0f -7.2288186904958804f   // -log2(150)
#define LN2f 0.69314718055994531f
#define SIGMAf 1.0e-4f
#define NEG_BIG -1.0e30f

// Threefry-2x32, 20 rounds, exactly as JAX's threefry2x32 lowering.
__host__ __device__ __forceinline__ void tf2x32(uint32_t k0, uint32_t k1,
                                                uint32_t x0, uint32_t x1,
                                                uint32_t& o0, uint32_t& o1) {
  uint32_t ks2 = k0 ^ k1 ^ 0x1BD11BDAu;
  x0 += k0; x1 += k1;
#define TFR(r) { x0 += x1; x1 = (x1 << r) | (x1 >> (32 - r)); x1 ^= x0; }
  TFR(13) TFR(15) TFR(26) TFR(6)
  x0 += k1;  x1 += ks2 + 1u;
  TFR(17) TFR(29) TFR(16) TFR(24)
  x0 += ks2; x1 += k0 + 2u;
  TFR(13) TFR(15) TFR(26) TFR(6)
  x0 += k0;  x1 += k1 + 3u;
  TFR(17) TFR(29) TFR(16) TFR(24)
  x0 += k1;  x1 += ks2 + 4u;
  TFR(13) TFR(15) TFR(26) TFR(6)
  x0 += ks2; x1 += k0 + 5u;
#undef TFR
  o0 = x0; o1 = x1;
}

__device__ __forceinline__ uint32_t jax_bits(uint32_t k0, uint32_t k1, uint32_t p) {
#if JAX_PARTITIONABLE
  uint32_t a, b; tf2x32(k0, k1, 0u, p, a, b);   // counter = (hi=0, lo=p)
  return a ^ b;
#else
  uint32_t a, b; tf2x32(k0, k1, 0u, p, a, b);
  return a ^ b;
#endif
}

__global__ __launch_bounds__(NT) void cfm_ot_kernel(
    const float* __restrict__ x1g, const float* __restrict__ maskg,
    const float* __restrict__ tg, const float* __restrict__ x0g,
    const float* __restrict__ epsg,
    const float* __restrict__ W1, const float* __restrict__ b1,
    const float* __restrict__ W2, const float* __restrict__ b2,
    float* __restrict__ partials,
    uint32_t kj0, uint32_t kj1, uint32_t k1r0, uint32_t k1r1,
    uint32_t k2r0, uint32_t k2r1)
{
  extern __shared__ float sm[];
  float* Mn  = sm;                     // [160][152] = 24320 floats, -M*log2e/eps
  float* x1L = Mn + RPAD * STR2;       // 456
  float* x0L = x1L + 456;              // 456
  float* phi = x0L + 456;              // 160  (f * log2e/eps), pad rows = 0
  float* psi = phi + 160;              // 160  (g * log2e/eps), pad cols = NEG_BIG
  float* red = psi + 160;              // 16
  float4* Mn4  = (float4*)Mn;          // row stride 38 float4
  float4* psi4 = (float4*)psi;

  const int b    = blockIdx.x;
  const int tid  = threadIdx.x;
  const int lane = tid & 63;
  const int wid  = tid >> 6;

  // ---- init: Mn = NEG_BIG (padding survives), x tiles, phi/psi ----
  {
    const float4 nb = make_float4(NEG_BIG, NEG_BIG, NEG_BIG, NEG_BIG);
    #pragma unroll
    for (int k = 0; k < 10; ++k) {
      const int idx = tid + NT * k;
      if (idx < RPAD * STR2 / 4) Mn4[idx] = nb;
    }
  }
  if (tid < 450) {
    x1L[tid] = x1g[b * 450 + tid];
    x0L[tid] = x0g[b * 450 + tid];
  }
  if (tid < 160) { phi[tid] = 0.f; psi[tid] = NEG_BIG; }
  __syncthreads();

  // ---- squared distances D[i][j] into real region, track block max ----
  const int colD = tid >> 2;   // 0..159
  const int hD   = tid & 3;
  float lmax = 0.f;
  if (colD < N_) {
    const float a0 = x1L[colD * 3 + 0], a1 = x1L[colD * 3 + 1], a2 = x1L[colD * 3 + 2];
    #pragma unroll
    for (int k = 0; k < 38; ++k) {
      const int i = 38 * hD + k;
      if (i < N_) {
        const float dx = x0L[i * 3 + 0] - a0;
        const float dy = x0L[i * 3 + 1] - a1;
        const float dz = x0L[i * 3 + 2] - a2;
        const float d = fmaf(dz, dz, fmaf(dy, dy, dx * dx));
        Mn[i * STR2 + colD] = d;
        lmax = fmaxf(lmax, d);
      }
    }
  }
  #pragma unroll
  for (int off = 1; off < 64; off <<= 1) lmax = fmaxf(lmax, __shfl_xor(lmax, off));
  if (lane == 0) red[wid] = lmax;
  __syncthreads();
  if (tid == 0) {
    float m = red[0];
    #pragma unroll
    for (int w = 1; w < 10; ++w) m = fmaxf(m, red[w]);
    red[15] = -C1f / m;
  }
  __syncthreads();
  const float nsc = red[15];
  if (colD < N_) {
    #pragma unroll
    for (int k = 0; k < 38; ++k) {
      const int i = 38 * hD + k;
      if (i < N_) Mn[i * STR2 + colD] *= nsc;
    }
  }
  __syncthreads();

  // ---- phase-A register tile: thread (c4A, rA) owns cols 4c4A..+3, rows rA+16k ----
  const int c4A = tid >> 4;    // 0..39, active < 38
  const int rA  = tid & 15;
  const bool actA = (c4A < 38);
  float4 ca[10];
  if (actA) {
    #pragma unroll
    for (int k = 0; k < 10; ++k) ca[k] = Mn4[(rA + 16 * k) * 38 + c4A];
  }

  const int iB = tid >> 2;     // 0..159, active < 150 (tid < 600)
  const int qB = tid & 3;
  const bool actB = (tid < 600);

  // ---- 100 Sinkhorn iterations, log2 domain ----
  for (int it = 0; it < 100; ++it) {
    // phase A: psi_j = C0 - LSE2_i(phi_i + Mn[i][j]), per-column (register tile)
    if (actA) {
      float phiR[10];
      float4 m4 = make_float4(NEG_BIG, NEG_BIG, NEG_BIG, NEG_BIG);
      #pragma unroll
      for (int k = 0; k < 10; ++k) {
        phiR[k] = phi[rA + 16 * k];
        m4.x = fmaxf(m4.x, ca[k].x + phiR[k]);
        m4.y = fmaxf(m4.y, ca[k].y + phiR[k]);
        m4.z = fmaxf(m4.z, ca[k].z + phiR[k]);
        m4.w = fmaxf(m4.w, ca[k].w + phiR[k]);
      }
      #pragma unroll
      for (int off = 1; off < 16; off <<= 1) {
        m4.x = fmaxf(m4.x, __shfl_xor(m4.x, off));
        m4.y = fmaxf(m4.y, __shfl_xor(m4.y, off));
        m4.z = fmaxf(m4.z, __shfl_xor(m4.z, off));
        m4.w = fmaxf(m4.w, __shfl_xor(m4.w, off));
      }
      float4 s4 = make_float4(0.f, 0.f, 0.f, 0.f);
      #pragma unroll
      for (int k = 0; k < 10; ++k) {
        s4.x += exp2f(ca[k].x + phiR[k] - m4.x);
        s4.y += exp2f(ca[k].y + phiR[k] - m4.y);
        s4.z += exp2f(ca[k].z + phiR[k] - m4.z);
        s4.w += exp2f(ca[k].w + phiR[k] - m4.w);
      }
      #pragma unroll
      for (int off = 1; off < 16; off <<= 1) {
        s4.x += __shfl_xor(s4.x, off);
        s4.y += __shfl_xor(s4.y, off);
        s4.z += __shfl_xor(s4.z, off);
        s4.w += __shfl_xor(s4.w, off);
      }
      if (rA == 0) {
        float4 o;
        o.x = C0f - (m4.x + log2f(s4.x));
        o.y = C0f - (m4.y + log2f(s4.y));
        o.z = C0f - (m4.z + log2f(s4.z));
        o.w = C0f - (m4.w + log2f(s4.w));
        if (c4A < 37) psi4[c4A] = o;
        else { psi[148] = o.x; psi[149] = o.y; }   // keep psi[150..] = NEG_BIG
      }
    }
    __syncthreads();

    // phase B: phi_i = C0 - LSE2_j(psi_j + Mn[i][j]), per-row (b128 loads)
    if (actB) {
      float4 vb[10];
      #pragma unroll
      for (int k = 0; k < 10; ++k) {
        const int f = qB + 4 * k;
        if (f < 38) {
          const float4 a = Mn4[iB * 38 + f];
          const float4 p = psi4[f];
          vb[k].x = a.x + p.x; vb[k].y = a.y + p.y;
          vb[k].z = a.z + p.z; vb[k].w = a.w + p.w;
        } else {
          vb[k] = make_float4(NEG_BIG, NEG_BIG, NEG_BIG, NEG_BIG);
        }
      }
      float4 m4 = vb[0];
      #pragma unroll
      for (int k = 1; k < 10; ++k) {
        m4.x = fmaxf(m4.x, vb[k].x); m4.y = fmaxf(m4.y, vb[k].y);
        m4.z = fmaxf(m4.z, vb[k].z); m4.w = fmaxf(m4.w, vb[k].w);
      }
      float m = fmaxf(fmaxf(m4.x, m4.y), fmaxf(m4.z, m4.w));
      m = fmaxf(m, __shfl_xor(m, 1));
      m = fmaxf(m, __shfl_xor(m, 2));
      float s = 0.f;
      #pragma unroll
      for (int k = 0; k < 10; ++k) {
        s += exp2f(vb[k].x - m) + exp2f(vb[k].y - m)
           + exp2f(vb[k].z - m) + exp2f(vb[k].w - m);
      }
      s += __shfl_xor(s, 1);
      s += __shfl_xor(s, 2);
      if (qB == 0 && iB < N_) phi[iB] = C0f - (m + log2f(s));
    }
    __syncthreads();
  }

  // ---- sampling + MLP + loss: one wave per sample n ----
  const float tb = tg[b];
  float wacc = 0.f;
  for (int n = wid; n < N_; n += 10) {
    const uint32_t p = (uint32_t)(b * N_ + n);
    const uint32_t hb = jax_bits(k1r0, k1r1, p);
    const uint32_t lb = jax_bits(k2r0, k2r1, p);
    const int isel = (int)(((hb % 150u) * 46u + (lb % 150u)) % 150u);
    const float phi_i = phi[isel];
    const float* MnRow = Mn + isel * STR2;

    float best = -1e30f; int bestk = 0x7fffffff;
    #pragma unroll
    for (int c2 = 0; c2 < 3; ++c2) {
      const int k = lane + 64 * c2;
      if (k < N_) {
        const uint32_t bits = jax_bits(kj0, kj1, p * 150u + (uint32_t)k);
        float u = __uint_as_float((bits >> 9) | 0x3F800000u) - 1.0f;
        u = fmaxf(u, 1.17549435e-38f);
        const float g = -logf(-logf(u));
        const float val = fmaf(phi_i + psi[k] + MnRow[k], LN2f, g);
        if (val > best || (val == best && k < bestk)) { best = val; bestk = k; }
      }
    }
    #pragma unroll
    for (int off = 1; off < 64; off <<= 1) {
      const float ov = __shfl_xor(best, off);
      const int   ok = __shfl_xor(bestk, off);
      if (ov > best || (ov == best && ok < bestk)) { best = ov; bestk = ok; }
    }
    const int j = bestk;

    const float mot = maskg[b * N_ + j];
    const float p0 = x0L[isel * 3 + 0], p1 = x0L[isel * 3 + 1], p2 = x0L[isel * 3 + 2];
    const float q0 = x1L[j * 3 + 0],    q1 = x1L[j * 3 + 1],    q2 = x1L[j * 3 + 2];
    const float omt = 1.f - tb;
    const float y0 = p0 * tb + q0 * omt + SIGMAf * epsg[b * 450 + n * 3 + 0];
    const float y1 = p1 * tb + q1 * omt + SIGMAf * epsg[b * 450 + n * 3 + 1];
    const float y2 = p2 * tb + q2 * omt + SIGMAf * epsg[b * 450 + n * 3 + 2];
    const float u0 = (p0 - q0) * mot, u1 = (p1 - q1) * mot, u2 = (p2 - q2) * mot;

    float a0 = 0.f, a1 = 0.f, a2 = 0.f;
    #pragma unroll
    for (int qq = 0; qq < 8; ++qq) {
      const int hd = 64 * qq + lane;
      float z = b1[hd];
      z = fmaf(y0, W1[hd],        z);
      z = fmaf(y1, W1[512 + hd],  z);
      z = fmaf(y2, W1[1024 + hd], z);
      z = fmaf(tb, W1[1536 + hd], z);
      const float zc = fmaf(0.044715f * z, z * z, z);
      const float th = tanhf(0.7978845608028654f * zc);
      const float ge = 0.5f * z * (1.f + th);
      a0 = fmaf(ge, W2[hd * 3 + 0], a0);
      a1 = fmaf(ge, W2[hd * 3 + 1], a1);
      a2 = fmaf(ge, W2[hd * 3 + 2], a2);
    }
    #pragma unroll
    for (int off = 1; off < 64; off <<= 1) {
      a0 += __shfl_xor(a0, off);
      a1 += __shfl_xor(a1, off);
      a2 += __shfl_xor(a2, off);
    }
    const float v0 = (a0 + b2[0]) * mot;
    const float v1 = (a1 + b2[1]) * mot;
    const float v2 = (a2 + b2[2]) * mot;
    const float d0 = v0 - u0, d1 = v1 - u1, d2 = v2 - u2;
    wacc += fmaf(d2, d2, fmaf(d1, d1, d0 * d0));
  }

  if (lane == 0) red[wid] = wacc;
  __syncthreads();
  if (tid == 0) {
    float s = 0.f;
    #pragma unroll
    for (int w = 0; w < 10; ++w) s += red[w];
    partials[b] = s;
  }
}

__global__ void cfm_reduce_kernel(const float* __restrict__ partials,
                                  float* __restrict__ out) {
  const int tid = threadIdx.x;   // 64 threads
  float s = 0.f;
  #pragma unroll
  for (int q = 0; q < 8; ++q) s += partials[tid + 64 * q];
  #pragma unroll
  for (int off = 1; off < 64; off <<= 1) s += __shfl_xor(s, off);
  if (tid == 0) out[0] = s * (1.0f / 230400.0f);
}

extern "C" void kernel_launch(void* const* d_in, const int* in_sizes, int n_in,
                              void* d_out, int out_size, void* d_ws, size_t ws_size,
                              hipStream_t stream) {
  (void)in_sizes; (void)n_in; (void)out_size; (void)ws_size;
  const float* x    = (const float*)d_in[0];
  const float* mask = (const float*)d_in[1];
  const float* t    = (const float*)d_in[2];
  const float* x0n  = (const float*)d_in[3];
  const float* epsn = (const float*)d_in[4];
  const float* W1   = (const float*)d_in[5];
  const float* b1   = (const float*)d_in[6];
  const float* W2   = (const float*)d_in[7];
  const float* b2   = (const float*)d_in[8];
  float* out = (float*)d_out;
  float* partials = (float*)d_ws;

  uint32_t ki0, ki1, kj0, kj1, k1r0, k1r1, k2r0, k2r1;
  tf2x32(0u, 42u, 0u, 0u, ki0, ki1);
  tf2x32(0u, 42u, 0u, 1u, kj0, kj1);
  tf2x32(ki0, ki1, 0u, 0u, k1r0, k1r1);
  tf2x32(ki0, ki1, 0u, 1u, k2r0, k2r1);

  const int SMEM = (RPAD * STR2 + 456 + 456 + 160 + 160 + 16) * (int)sizeof(float);
  (void)hipFuncSetAttribute(reinterpret_cast<const void*>(cfm_ot_kernel),
                            hipFuncAttributeMaxDynamicSharedMemorySize, SMEM);
  cfm_ot_kernel<<<512, NT, SMEM, stream>>>(x, mask, t, x0n, epsn, W1, b1, W2, b2,
                                           partials, kj0, kj1, k1r0, k1r1, k2r0, k2r1);
  cfm_reduce_kernel<<<1, 64, 0, stream>>>(partials, out);
}

// Round 3
// 744.338 us; speedup vs baseline: 1.6661x; 1.5227x over previous
//
#include <hip/hip_runtime.h>
#include <cstdint>

#define B_ 512
#define N_ 150
#define NT 640
#define RPAD 160           // padded rows
#define CPAD 160           // padded cols (float4-tileable: 40 float4/row)
#define C1f 144.26950408889634f    // log2(e)/eps, eps=0.01
#define C0f -7.2288186904958804f   // -log2(150)
#define LN2f 0.69314718055994531f
#define SIGMAf 1.0e-4f
#define NEG_BIG -1.0e30f

// raw hardware transcendentals (1-ULP v_exp_f32 / v_log_f32; args are safe:
// exp2 args <= 0 (flush-to-zero wanted), log2 args in [1, 160])
#define EXP2R(x) __builtin_amdgcn_exp2f(x)
#define LOG2R(x) __builtin_amdgcn_logf(x)

// DPP lane permutes (VALU, not LDS pipe). 16-lane xor-tree:
// quad_perm xor1 (0xB1), quad_perm xor2 (0x4E), row_half_mirror (0x141, ==xor7
// which acts as xor4 once the quad is reduced), row_mirror (0x140, ==xor15 ->
// xor8 once the 8-group is reduced).
#define DPPF(v, c) __int_as_float(__builtin_amdgcn_update_dpp( \
    __float_as_int(v), __float_as_int(v), (c), 0xF, 0xF, false))
#define RED16_MAX(v) { v = fmaxf(v, DPPF(v, 0xB1)); v = fmaxf(v, DPPF(v, 0x4E)); \
                       v = fmaxf(v, DPPF(v, 0x141)); v = fmaxf(v, DPPF(v, 0x140)); }
#define RED16_ADD(v) { v = v + DPPF(v, 0xB1); v = v + DPPF(v, 0x4E); \
                       v = v + DPPF(v, 0x141); v = v + DPPF(v, 0x140); }
#define RED4_MAX(v)  { v = fmaxf(v, DPPF(v, 0xB1)); v = fmaxf(v, DPPF(v, 0x4E)); }
#define RED4_ADD(v)  { v = v + DPPF(v, 0xB1); v = v + DPPF(v, 0x4E); }

// Threefry-2x32, 20 rounds, exactly as JAX's threefry2x32 lowering.
__host__ __device__ __forceinline__ void tf2x32(uint32_t k0, uint32_t k1,
                                                uint32_t x0, uint32_t x1,
                                                uint32_t& o0, uint32_t& o1) {
  uint32_t ks2 = k0 ^ k1 ^ 0x1BD11BDAu;
  x0 += k0; x1 += k1;
#define TFR(r) { x0 += x1; x1 = (x1 << r) | (x1 >> (32 - r)); x1 ^= x0; }
  TFR(13) TFR(15) TFR(26) TFR(6)
  x0 += k1;  x1 += ks2 + 1u;
  TFR(17) TFR(29) TFR(16) TFR(24)
  x0 += ks2; x1 += k0 + 2u;
  TFR(13) TFR(15) TFR(26) TFR(6)
  x0 += k0;  x1 += k1 + 3u;
  TFR(17) TFR(29) TFR(16) TFR(24)
  x0 += k1;  x1 += ks2 + 4u;
  TFR(13) TFR(15) TFR(26) TFR(6)
  x0 += ks2; x1 += k0 + 5u;
#undef TFR
  o0 = x0; o1 = x1;
}

__device__ __forceinline__ uint32_t jax_bits(uint32_t k0, uint32_t k1, uint32_t p) {
  uint32_t a, b; tf2x32(k0, k1, 0u, p, a, b);   // partitionable: counter (0, p)
  return a ^ b;
}

__global__ __launch_bounds__(NT) void cfm_ot_kernel(
    const float* __restrict__ x1g, const float* __restrict__ maskg,
    const float* __restrict__ tg, const float* __restrict__ x0g,
    const float* __restrict__ epsg,
    const float* __restrict__ W1, const float* __restrict__ b1,
    const float* __restrict__ W2, const float* __restrict__ b2,
    float* __restrict__ partials,
    uint32_t kj0, uint32_t kj1, uint32_t k1r0, uint32_t k1r1,
    uint32_t k2r0, uint32_t k2r1)
{
  extern __shared__ float sm[];
  float* Mn  = sm;                     // [160][160], -M*log2e/eps, pads NEG_BIG
  float* x1L = Mn + RPAD * CPAD;       // 456
  float* x0L = x1L + 456;              // 456
  float* phi = x0L + 456;              // 160, pads stay 0
  float* psi = phi + 160;              // 160, pads stay NEG_BIG
  float* red = psi + 160;              // 16
  float4* Mn4  = (float4*)Mn;          // row stride 40 float4
  float4* psi4 = (float4*)psi;

  const int b    = blockIdx.x;
  const int tid  = threadIdx.x;
  const int lane = tid & 63;
  const int wid  = tid >> 6;

  // ---- init: Mn = NEG_BIG everywhere (pads survive), x tiles, phi/psi ----
  {
    const float4 nb = make_float4(NEG_BIG, NEG_BIG, NEG_BIG, NEG_BIG);
    #pragma unroll
    for (int k = 0; k < 10; ++k) Mn4[tid + NT * k] = nb;   // 6400 = 640*10
  }
  if (tid < 450) {
    x1L[tid] = x1g[b * 450 + tid];
    x0L[tid] = x0g[b * 450 + tid];
  }
  if (tid < 160) { phi[tid] = 0.f; psi[tid] = NEG_BIG; }
  __syncthreads();

  // ---- squared distances D[i][j] into real region, track block max ----
  const int colD = tid >> 2;   // 0..159
  const int hD   = tid & 3;
  float lmax = 0.f;
  if (colD < N_) {
    const float a0 = x1L[colD * 3 + 0], a1 = x1L[colD * 3 + 1], a2 = x1L[colD * 3 + 2];
    #pragma unroll
    for (int k = 0; k < 38; ++k) {
      const int i = 38 * hD + k;
      if (i < N_) {
        const float dx = x0L[i * 3 + 0] - a0;
        const float dy = x0L[i * 3 + 1] - a1;
        const float dz = x0L[i * 3 + 2] - a2;
        const float d = fmaf(dz, dz, fmaf(dy, dy, dx * dx));
        Mn[i * CPAD + colD] = d;
        lmax = fmaxf(lmax, d);
      }
    }
  }
  #pragma unroll
  for (int off = 1; off < 64; off <<= 1) lmax = fmaxf(lmax, __shfl_xor(lmax, off));
  if (lane == 0) red[wid] = lmax;
  __syncthreads();
  if (tid == 0) {
    float m = red[0];
    #pragma unroll
    for (int w = 1; w < 10; ++w) m = fmaxf(m, red[w]);
    red[15] = -C1f / m;
  }
  __syncthreads();
  const float nsc = red[15];
  if (colD < N_) {
    #pragma unroll
    for (int k = 0; k < 38; ++k) {
      const int i = 38 * hD + k;
      if (i < N_) Mn[i * CPAD + colD] *= nsc;
    }
  }
  __syncthreads();

  // ---- register tiles: whole matrix lives in VGPRs twice ----
  // phase A (column LSE): thread (c4A = tid>>4 in 0..39, rA = tid&15) owns
  //   cols 4*c4A..+3, rows rA+16k, k=0..9  -> ca[10] (float4 over 4 cols)
  // phase B (row LSE): thread (iB = tid>>2 in 0..159, qB = tid&3) owns
  //   row iB, cols 40*qB..+39 -> rb[10]
  const int c4A = tid >> 4;
  const int rA  = tid & 15;
  const int iB  = tid >> 2;
  const int qB  = tid & 3;
  float4 ca[10], rb[10];
  #pragma unroll
  for (int k = 0; k < 10; ++k) ca[k] = Mn4[(rA + 16 * k) * 40 + c4A];
  #pragma unroll
  for (int k = 0; k < 10; ++k) rb[k] = Mn4[iB * 40 + 10 * qB + k];

  // ---- 100 Sinkhorn iterations, log2 domain; LDS touched only for phi/psi ----
  for (int it = 0; it < 100; ++it) {
    // phase A: psi_j = C0 - LSE2_i(phi_i + Mn[i][j])
    {
      float4 tm[10];
      float4 m4 = make_float4(NEG_BIG, NEG_BIG, NEG_BIG, NEG_BIG);
      #pragma unroll
      for (int k = 0; k < 10; ++k) {
        const float ph = phi[rA + 16 * k];
        tm[k].x = ca[k].x + ph; tm[k].y = ca[k].y + ph;
        tm[k].z = ca[k].z + ph; tm[k].w = ca[k].w + ph;
        m4.x = fmaxf(m4.x, tm[k].x); m4.y = fmaxf(m4.y, tm[k].y);
        m4.z = fmaxf(m4.z, tm[k].z); m4.w = fmaxf(m4.w, tm[k].w);
      }
      RED16_MAX(m4.x) RED16_MAX(m4.y) RED16_MAX(m4.z) RED16_MAX(m4.w)
      float4 s4 = make_float4(0.f, 0.f, 0.f, 0.f);
      #pragma unroll
      for (int k = 0; k < 10; ++k) {
        s4.x += EXP2R(tm[k].x - m4.x); s4.y += EXP2R(tm[k].y - m4.y);
        s4.z += EXP2R(tm[k].z - m4.z); s4.w += EXP2R(tm[k].w - m4.w);
      }
      RED16_ADD(s4.x) RED16_ADD(s4.y) RED16_ADD(s4.z) RED16_ADD(s4.w)
      if (rA == 0) {
        float4 o;
        o.x = C0f - (m4.x + LOG2R(s4.x));
        o.y = C0f - (m4.y + LOG2R(s4.y));
        o.z = C0f - (m4.z + LOG2R(s4.z));
        o.w = C0f - (m4.w + LOG2R(s4.w));
        if (c4A < 37) psi4[c4A] = o;
        else if (c4A == 37) { psi[148] = o.x; psi[149] = o.y; }  // cols 150+ stay NEG
      }
    }
    __syncthreads();

    // phase B: phi_i = C0 - LSE2_j(psi_j + Mn[i][j])
    {
      float4 tm[10];
      float4 m4 = make_float4(NEG_BIG, NEG_BIG, NEG_BIG, NEG_BIG);
      #pragma unroll
      for (int k = 0; k < 10; ++k) {
        const float4 p = psi4[10 * qB + k];
        tm[k].x = rb[k].x + p.x; tm[k].y = rb[k].y + p.y;
        tm[k].z = rb[k].z + p.z; tm[k].w = rb[k].w + p.w;
        m4.x = fmaxf(m4.x, tm[k].x); m4.y = fmaxf(m4.y, tm[k].y);
        m4.z = fmaxf(m4.z, tm[k].z); m4.w = fmaxf(m4.w, tm[k].w);
      }
      float m = fmaxf(fmaxf(m4.x, m4.y), fmaxf(m4.z, m4.w));
      RED4_MAX(m)
      float s = 0.f;
      #pragma unroll
      for (int k = 0; k < 10; ++k) {
        s += EXP2R(tm[k].x - m) + EXP2R(tm[k].y - m)
           + EXP2R(tm[k].z - m) + EXP2R(tm[k].w - m);
      }
      RED4_ADD(s)
      if (qB == 0 && iB < N_) phi[iB] = C0f - (m + LOG2R(s));
    }
    __syncthreads();
  }

  // ---- sampling + MLP + loss: one wave per sample n ----
  const float tb = tg[b];
  float wacc = 0.f;
  for (int n = wid; n < N_; n += 10) {
    const uint32_t p = (uint32_t)(b * N_ + n);
    const uint32_t hb = jax_bits(k1r0, k1r1, p);
    const uint32_t lb = jax_bits(k2r0, k2r1, p);
    const int isel = (int)(((hb % 150u) * 46u + (lb % 150u)) % 150u);
    const float phi_i = phi[isel];
    const float* MnRow = Mn + isel * CPAD;

    float best = -1e30f; int bestk = 0x7fffffff;
    #pragma unroll
    for (int c2 = 0; c2 < 3; ++c2) {
      const int k = lane + 64 * c2;
      if (k < N_) {
        const uint32_t bits = jax_bits(kj0, kj1, p * 150u + (uint32_t)k);
        float u = __uint_as_float((bits >> 9) | 0x3F800000u) - 1.0f;
        u = fmaxf(u, 1.17549435e-38f);
        const float g = -logf(-logf(u));
        const float val = fmaf(phi_i + psi[k] + MnRow[k], LN2f, g);
        if (val > best || (val == best && k < bestk)) { best = val; bestk = k; }
      }
    }
    #pragma unroll
    for (int off = 1; off < 64; off <<= 1) {
      const float ov = __shfl_xor(best, off);
      const int   ok = __shfl_xor(bestk, off);
      if (ov > best || (ov == best && ok < bestk)) { best = ov; bestk = ok; }
    }
    const int j = bestk;

    const float mot = maskg[b * N_ + j];
    const float p0 = x0L[isel * 3 + 0], p1 = x0L[isel * 3 + 1], p2 = x0L[isel * 3 + 2];
    const float q0 = x1L[j * 3 + 0],    q1 = x1L[j * 3 + 1],    q2 = x1L[j * 3 + 2];
    const float omt = 1.f - tb;
    const float y0 = p0 * tb + q0 * omt + SIGMAf * epsg[b * 450 + n * 3 + 0];
    const float y1 = p1 * tb + q1 * omt + SIGMAf * epsg[b * 450 + n * 3 + 1];
    const float y2 = p2 * tb + q2 * omt + SIGMAf * epsg[b * 450 + n * 3 + 2];
    const float u0 = (p0 - q0) * mot, u1 = (p1 - q1) * mot, u2 = (p2 - q2) * mot;

    float a0 = 0.f, a1 = 0.f, a2 = 0.f;
    #pragma unroll
    for (int qq = 0; qq < 8; ++qq) {
      const int hd = 64 * qq + lane;
      float z = b1[hd];
      z = fmaf(y0, W1[hd],        z);
      z = fmaf(y1, W1[512 + hd],  z);
      z = fmaf(y2, W1[1024 + hd], z);
      z = fmaf(tb, W1[1536 + hd], z);
      const float zc = fmaf(0.044715f * z, z * z, z);
      const float th = tanhf(0.7978845608028654f * zc);
      const float ge = 0.5f * z * (1.f + th);
      a0 = fmaf(ge, W2[hd * 3 + 0], a0);
      a1 = fmaf(ge, W2[hd * 3 + 1], a1);
      a2 = fmaf(ge, W2[hd * 3 + 2], a2);
    }
    #pragma unroll
    for (int off = 1; off < 64; off <<= 1) {
      a0 += __shfl_xor(a0, off);
      a1 += __shfl_xor(a1, off);
      a2 += __shfl_xor(a2, off);
    }
    const float v0 = (a0 + b2[0]) * mot;
    const float v1 = (a1 + b2[1]) * mot;
    const float v2 = (a2 + b2[2]) * mot;
    const float d0 = v0 - u0, d1 = v1 - u1, d2 = v2 - u2;
    wacc += fmaf(d2, d2, fmaf(d1, d1, d0 * d0));
  }

  if (lane == 0) red[wid] = wacc;
  __syncthreads();
  if (tid == 0) {
    float s = 0.f;
    #pragma unroll
    for (int w = 0; w < 10; ++w) s += red[w];
    partials[b] = s;
  }
}

__global__ void cfm_reduce_kernel(const float* __restrict__ partials,
                                  float* __restrict__ out) {
  const int tid = threadIdx.x;   // 64 threads
  float s = 0.f;
  #pragma unroll
  for (int q = 0; q < 8; ++q) s += partials[tid + 64 * q];
  #pragma unroll
  for (int off = 1; off < 64; off <<= 1) s += __shfl_xor(s, off);
  if (tid == 0) out[0] = s * (1.0f / 230400.0f);
}

extern "C" void kernel_launch(void* const* d_in, const int* in_sizes, int n_in,
                              void* d_out, int out_size, void* d_ws, size_t ws_size,
                              hipStream_t stream) {
  (void)in_sizes; (void)n_in; (void)out_size; (void)ws_size;
  const float* x    = (const float*)d_in[0];
  const float* mask = (const float*)d_in[1];
  const float* t    = (const float*)d_in[2];
  const float* x0n  = (const float*)d_in[3];
  const float* epsn = (const float*)d_in[4];
  const float* W1   = (const float*)d_in[5];
  const float* b1   = (const float*)d_in[6];
  const float* W2   = (const float*)d_in[7];
  const float* b2   = (const float*)d_in[8];
  float* out = (float*)d_out;
  float* partials = (float*)d_ws;

  uint32_t ki0, ki1, kj0, kj1, k1r0, k1r1, k2r0, k2r1;
  tf2x32(0u, 42u, 0u, 0u, ki0, ki1);
  tf2x32(0u, 42u, 0u, 1u, kj0, kj1);
  tf2x32(ki0, ki1, 0u, 0u, k1r0, k1r1);
  tf2x32(ki0, ki1, 0u, 1u, k2r0, k2r1);

  const int SMEM = (RPAD * CPAD + 456 + 456 + 160 + 160 + 16) * (int)sizeof(float);
  (void)hipFuncSetAttribute(reinterpret_cast<const void*>(cfm_ot_kernel),
                            hipFuncAttributeMaxDynamicSharedMemorySize, SMEM);
  cfm_ot_kernel<<<512, NT, SMEM, stream>>>(x, mask, t, x0n, epsn, W1, b1, W2, b2,
                                           partials, kj0, kj1, k1r0, k1r1, k2r0, k2r1);
  cfm_reduce_kernel<<<1, 64, 0, stream>>>(partials, out);
}

// Round 4
// 632.871 us; speedup vs baseline: 1.9595x; 1.1761x over previous
//
#include <hip/hip_runtime.h>
#include <cstdint>

#define B_ 512
#define N_ 150
#define NT 640
#define RPAD 160           // padded rows
#define CPAD 160           // padded cols (40 float4/row)
#define C1f 144.26950408889634f    // log2(e)/eps, eps=0.01
#define C0f -7.2288186904958804f   // -log2(150)
#define LN2f 0.69314718055994531f
#define SIGMAf 1.0e-4f
#define NEG_BIG -1.0e30f

// raw hardware transcendentals (1-ULP v_exp_f32 / v_log_f32)
#define EXP2R(x) __builtin_amdgcn_exp2f(x)
#define LOG2R(x) __builtin_amdgcn_logf(x)

// DPP quad-perm reduces (VALU pipe, 2-cyc): xor1 = 0xB1, xor2 = 0x4E
#define DPPF(v, c) __int_as_float(__builtin_amdgcn_update_dpp( \
    __float_as_int(v), __float_as_int(v), (c), 0xF, 0xF, false))
#define RED4_MAX(v)  { v = fmaxf(v, DPPF(v, 0xB1)); v = fmaxf(v, DPPF(v, 0x4E)); }
#define RED4_ADD(v)  { v = v + DPPF(v, 0xB1); v = v + DPPF(v, 0x4E); }

// force a float4 to stay in VGPRs (compiler cannot rematerialize past this)
#define KEEP4(v) asm volatile("" : "+v"(v.x), "+v"(v.y), "+v"(v.z), "+v"(v.w))

// Threefry-2x32, 20 rounds, exactly as JAX's threefry2x32 lowering.
__host__ __device__ __forceinline__ void tf2x32(uint32_t k0, uint32_t k1,
                                                uint32_t x0, uint32_t x1,
                                                uint32_t& o0, uint32_t& o1) {
  uint32_t ks2 = k0 ^ k1 ^ 0x1BD11BDAu;
  x0 += k0; x1 += k1;
#define TFR(r) { x0 += x1; x1 = (x1 << r) | (x1 >> (32 - r)); x1 ^= x0; }
  TFR(13) TFR(15) TFR(26) TFR(6)
  x0 += k1;  x1 += ks2 + 1u;
  TFR(17) TFR(29) TFR(16) TFR(24)
  x0 += ks2; x1 += k0 + 2u;
  TFR(13) TFR(15) TFR(26) TFR(6)
  x0 += k0;  x1 += k1 + 3u;
  TFR(17) TFR(29) TFR(16) TFR(24)
  x0 += k1;  x1 += ks2 + 4u;
  TFR(13) TFR(15) TFR(26) TFR(6)
  x0 += ks2; x1 += k0 + 5u;
#undef TFR
  o0 = x0; o1 = x1;
}

__device__ __forceinline__ uint32_t jax_bits(uint32_t k0, uint32_t k1, uint32_t p) {
  uint32_t a, b; tf2x32(k0, k1, 0u, p, a, b);   // partitionable: counter (0, p)
  return a ^ b;
}

__global__ __launch_bounds__(NT) void cfm_ot_kernel(
    const float* __restrict__ x1g, const float* __restrict__ maskg,
    const float* __restrict__ tg, const float* __restrict__ x0g,
    const float* __restrict__ epsg,
    const float* __restrict__ W1, const float* __restrict__ b1,
    const float* __restrict__ W2, const float* __restrict__ b2,
    float* __restrict__ partials,
    uint32_t kj0, uint32_t kj1, uint32_t k1r0, uint32_t k1r1,
    uint32_t k2r0, uint32_t k2r1)
{
  extern __shared__ float sm[];
  float* Mn  = sm;                     // [160][160], -M*log2e/eps, pads NEG_BIG
  float* x1L = Mn + RPAD * CPAD;       // 456
  float* x0L = x1L + 456;              // 456
  float* phi = x0L + 456;              // 160, pads stay 0
  float* psi = phi + 160;              // 160, pads stay NEG_BIG
  float* red = psi + 160;              // 16
  float4* Mn4  = (float4*)Mn;          // row stride 40 float4
  float4* phi4 = (float4*)phi;
  float4* psi4 = (float4*)psi;

  const int b    = blockIdx.x;
  const int tid  = threadIdx.x;
  const int lane = tid & 63;
  const int wid  = tid >> 6;

  // ---- init: Mn = NEG_BIG everywhere (pads survive), x tiles, phi/psi ----
  {
    const float4 nb = make_float4(NEG_BIG, NEG_BIG, NEG_BIG, NEG_BIG);
    #pragma unroll
    for (int k = 0; k < 10; ++k) Mn4[tid + NT * k] = nb;   // 6400 = 640*10
  }
  if (tid < 450) {
    x1L[tid] = x1g[b * 450 + tid];
    x0L[tid] = x0g[b * 450 + tid];
  }
  if (tid < 160) { phi[tid] = 0.f; psi[tid] = NEG_BIG; }
  __syncthreads();

  // ---- squared distances D[i][j], track block max ----
  const int colD = tid >> 2;   // 0..159
  const int hD   = tid & 3;
  float lmax = 0.f;
  if (colD < N_) {
    const float a0 = x1L[colD * 3 + 0], a1 = x1L[colD * 3 + 1], a2 = x1L[colD * 3 + 2];
    #pragma unroll
    for (int k = 0; k < 38; ++k) {
      const int i = 38 * hD + k;
      if (i < N_) {
        const float dx = x0L[i * 3 + 0] - a0;
        const float dy = x0L[i * 3 + 1] - a1;
        const float dz = x0L[i * 3 + 2] - a2;
        const float d = fmaf(dz, dz, fmaf(dy, dy, dx * dx));
        Mn[i * CPAD + colD] = d;
        lmax = fmaxf(lmax, d);
      }
    }
  }
  #pragma unroll
  for (int off = 1; off < 64; off <<= 1) lmax = fmaxf(lmax, __shfl_xor(lmax, off));
  if (lane == 0) red[wid] = lmax;
  __syncthreads();
  if (tid == 0) {
    float m = red[0];
    #pragma unroll
    for (int w = 1; w < 10; ++w) m = fmaxf(m, red[w]);
    red[15] = -C1f / m;
  }
  __syncthreads();
  const float nsc = red[15];
  if (colD < N_) {
    #pragma unroll
    for (int k = 0; k < 38; ++k) {
      const int i = 38 * hD + k;
      if (i < N_) Mn[i * CPAD + colD] *= nsc;
    }
  }
  __syncthreads();

  // ---- register tiles (whole matrix in VGPRs, twice), forced resident ----
  // phase A: thread (jA = tid>>2, qA = tid&3) owns col jA, rows 40qA..+39
  //          ca[k] = Mn[40qA+4k .. +3][jA]   (one-time strided scalar loads)
  // phase B: thread (iB = tid>>2, qB = tid&3) owns row iB, cols 40qB..+39
  //          rb[k] = Mn[iB][40qB+4k .. +3]   (b128 loads)
  const int jA = tid >> 2;
  const int qA = tid & 3;
  float4 ca[10], rb[10];
  {
    const int rbase = 40 * qA;
    #pragma unroll
    for (int k = 0; k < 10; ++k) {
      ca[k].x = Mn[(rbase + 4 * k + 0) * CPAD + jA];
      ca[k].y = Mn[(rbase + 4 * k + 1) * CPAD + jA];
      ca[k].z = Mn[(rbase + 4 * k + 2) * CPAD + jA];
      ca[k].w = Mn[(rbase + 4 * k + 3) * CPAD + jA];
      KEEP4(ca[k]);
    }
    #pragma unroll
    for (int k = 0; k < 10; ++k) {
      rb[k] = Mn4[jA * 40 + 10 * qA + k];
      KEEP4(rb[k]);
    }
  }
  const int pbase = 10 * qA;   // float4 index base into phi4/psi4

  // ---- 100 Sinkhorn iterations, log2 domain ----
  for (int it = 0; it < 100; ++it) {
    // phase A: psi_j = C0 - LSE2_i(phi_i + Mn[i][j]) ; quad-reduce over i
    {
      float4 tm[10];
      float m = NEG_BIG;
      #pragma unroll
      for (int k = 0; k < 10; ++k) {
        const float4 p = phi4[pbase + k];
        tm[k].x = ca[k].x + p.x; tm[k].y = ca[k].y + p.y;
        tm[k].z = ca[k].z + p.z; tm[k].w = ca[k].w + p.w;
        m = fmaxf(m, fmaxf(tm[k].x, tm[k].y));    // -> v_max3
        m = fmaxf(m, fmaxf(tm[k].z, tm[k].w));
      }
      RED4_MAX(m)
      float s0 = 0.f, s1 = 0.f;
      #pragma unroll
      for (int k = 0; k < 10; ++k) {
        s0 += EXP2R(tm[k].x - m) + EXP2R(tm[k].y - m);
        s1 += EXP2R(tm[k].z - m) + EXP2R(tm[k].w - m);
      }
      float s = s0 + s1;
      RED4_ADD(s)
      if (qA == 0 && jA < N_) psi[jA] = C0f - (m + LOG2R(s));
    }
    __syncthreads();

    // phase B: phi_i = C0 - LSE2_j(psi_j + Mn[i][j]) ; quad-reduce over j
    {
      float4 tm[10];
      float m = NEG_BIG;
      #pragma unroll
      for (int k = 0; k < 10; ++k) {
        const float4 p = psi4[pbase + k];
        tm[k].x = rb[k].x + p.x; tm[k].y = rb[k].y + p.y;
        tm[k].z = rb[k].z + p.z; tm[k].w = rb[k].w + p.w;
        m = fmaxf(m, fmaxf(tm[k].x, tm[k].y));
        m = fmaxf(m, fmaxf(tm[k].z, tm[k].w));
      }
      RED4_MAX(m)
      float s0 = 0.f, s1 = 0.f;
      #pragma unroll
      for (int k = 0; k < 10; ++k) {
        s0 += EXP2R(tm[k].x - m) + EXP2R(tm[k].y - m);
        s1 += EXP2R(tm[k].z - m) + EXP2R(tm[k].w - m);
      }
      float s = s0 + s1;
      RED4_ADD(s)
      if (qA == 0 && jA < N_) phi[jA] = C0f - (m + LOG2R(s));
    }
    __syncthreads();
  }

  // ---- sampling + MLP + loss: one wave per sample n ----
  const float tb = tg[b];
  float wacc = 0.f;
  for (int n = wid; n < N_; n += 10) {
    const uint32_t p = (uint32_t)(b * N_ + n);
    const uint32_t hb = jax_bits(k1r0, k1r1, p);
    const uint32_t lb = jax_bits(k2r0, k2r1, p);
    const int isel = (int)(((hb % 150u) * 46u + (lb % 150u)) % 150u);
    const float phi_i = phi[isel];
    const float* MnRow = Mn + isel * CPAD;

    float best = -1e30f; int bestk = 0x7fffffff;
    #pragma unroll
    for (int c2 = 0; c2 < 3; ++c2) {
      const int k = lane + 64 * c2;
      if (k < N_) {
        const uint32_t bits = jax_bits(kj0, kj1, p * 150u + (uint32_t)k);
        float u = __uint_as_float((bits >> 9) | 0x3F800000u) - 1.0f;
        u = fmaxf(u, 1.17549435e-38f);
        // gumbel = -log(-log u) via v_log_f32: -ln u = -LN2*log2(u)
        const float nlu = -LN2f * LOG2R(u);            // in (1.1e-7, 88]
        const float g = -LN2f * LOG2R(nlu);
        const float val = fmaf(phi_i + psi[k] + MnRow[k], LN2f, g);
        if (val > best || (val == best && k < bestk)) { best = val; bestk = k; }
      }
    }
    #pragma unroll
    for (int off = 1; off < 64; off <<= 1) {
      const float ov = __shfl_xor(best, off);
      const int   ok = __shfl_xor(bestk, off);
      if (ov > best || (ov == best && ok < bestk)) { best = ov; bestk = ok; }
    }
    const int j = bestk;

    const float mot = maskg[b * N_ + j];
    const float p0 = x0L[isel * 3 + 0], p1 = x0L[isel * 3 + 1], p2 = x0L[isel * 3 + 2];
    const float q0 = x1L[j * 3 + 0],    q1 = x1L[j * 3 + 1],    q2 = x1L[j * 3 + 2];
    const float omt = 1.f - tb;
    const float y0 = p0 * tb + q0 * omt + SIGMAf * epsg[b * 450 + n * 3 + 0];
    const float y1 = p1 * tb + q1 * omt + SIGMAf * epsg[b * 450 + n * 3 + 1];
    const float y2 = p2 * tb + q2 * omt + SIGMAf * epsg[b * 450 + n * 3 + 2];
    const float u0 = (p0 - q0) * mot, u1 = (p1 - q1) * mot, u2 = (p2 - q2) * mot;

    float a0 = 0.f, a1 = 0.f, a2 = 0.f;
    #pragma unroll
    for (int qq = 0; qq < 8; ++qq) {
      const int hd = 64 * qq + lane;
      float z = b1[hd];
      z = fmaf(y0, W1[hd],        z);
      z = fmaf(y1, W1[512 + hd],  z);
      z = fmaf(y2, W1[1024 + hd], z);
      z = fmaf(tb, W1[1536 + hd], z);
      // gelu(z) = z * sigmoid(2*0.79788456*(z + 0.044715 z^3))
      const float zc = fmaf(0.044715f * z, z * z, z);
      const float e2 = EXP2R(-2.3022082062161855f * zc);
      const float ge = z * __builtin_amdgcn_rcpf(1.f + e2);
      a0 = fmaf(ge, W2[hd * 3 + 0], a0);
      a1 = fmaf(ge, W2[hd * 3 + 1], a1);
      a2 = fmaf(ge, W2[hd * 3 + 2], a2);
    }
    #pragma unroll
    for (int off = 1; off < 64; off <<= 1) {
      a0 += __shfl_xor(a0, off);
      a1 += __shfl_xor(a1, off);
      a2 += __shfl_xor(a2, off);
    }
    const float v0 = (a0 + b2[0]) * mot;
    const float v1 = (a1 + b2[1]) * mot;
    const float v2 = (a2 + b2[2]) * mot;
    const float d0 = v0 - u0, d1 = v1 - u1, d2 = v2 - u2;
    wacc += fmaf(d2, d2, fmaf(d1, d1, d0 * d0));
  }

  if (lane == 0) red[wid] = wacc;
  __syncthreads();
  if (tid == 0) {
    float s = 0.f;
    #pragma unroll
    for (int w = 0; w < 10; ++w) s += red[w];
    partials[b] = s;
  }
}

__global__ void cfm_reduce_kernel(const float* __restrict__ partials,
                                  float* __restrict__ out) {
  const int tid = threadIdx.x;   // 64 threads
  float s = 0.f;
  #pragma unroll
  for (int q = 0; q < 8; ++q) s += partials[tid + 64 * q];
  #pragma unroll
  for (int off = 1; off < 64; off <<= 1) s += __shfl_xor(s, off);
  if (tid == 0) out[0] = s * (1.0f / 230400.0f);
}

extern "C" void kernel_launch(void* const* d_in, const int* in_sizes, int n_in,
                              void* d_out, int out_size, void* d_ws, size_t ws_size,
                              hipStream_t stream) {
  (void)in_sizes; (void)n_in; (void)out_size; (void)ws_size;
  const float* x    = (const float*)d_in[0];
  const float* mask = (const float*)d_in[1];
  const float* t    = (const float*)d_in[2];
  const float* x0n  = (const float*)d_in[3];
  const float* epsn = (const float*)d_in[4];
  const float* W1   = (const float*)d_in[5];
  const float* b1   = (const float*)d_in[6];
  const float* W2   = (const float*)d_in[7];
  const float* b2   = (const float*)d_in[8];
  float* out = (float*)d_out;
  float* partials = (float*)d_ws;

  uint32_t ki0, ki1, kj0, kj1, k1r0, k1r1, k2r0, k2r1;
  tf2x32(0u, 42u, 0u, 0u, ki0, ki1);
  tf2x32(0u, 42u, 0u, 1u, kj0, kj1);
  tf2x32(ki0, ki1, 0u, 0u, k1r0, k1r1);
  tf2x32(ki0, ki1, 0u, 1u, k2r0, k2r1);

  const int SMEM = (RPAD * CPAD + 456 + 456 + 160 + 160 + 16) * (int)sizeof(float);
  (void)hipFuncSetAttribute(reinterpret_cast<const void*>(cfm_ot_kernel),
                            hipFuncAttributeMaxDynamicSharedMemorySize, SMEM);
  cfm_ot_kernel<<<512, NT, SMEM, stream>>>(x, mask, t, x0n, epsn, W1, b1, W2, b2,
                                           partials, kj0, kj1, k1r0, k1r1, k2r0, k2r1);
  cfm_reduce_kernel<<<1, 64, 0, stream>>>(partials, out);
}

// Round 5
// 604.999 us; speedup vs baseline: 2.0498x; 1.0461x over previous
//
#include <hip/hip_runtime.h>
#include <cstdint>

#define B_ 512
#define N_ 150
#define NT 640
#define RPAD 160           // padded rows
#define CPAD 160           // padded cols (40 float4/row)
#define PPS 304            // per-b stride in pp buffer: 150 phi + 150 psi + nsc
#define C1f 144.26950408889634f    // log2(e)/eps, eps=0.01
#define C0f -7.2288186904958804f   // -log2(150)
#define LN2f 0.69314718055994531f
#define SIGMAf 1.0e-4f
#define NEG_BIG -1.0e30f

// raw hardware transcendentals (1-ULP v_exp_f32 / v_log_f32)
#define EXP2R(x) __builtin_amdgcn_exp2f(x)
#define LOG2R(x) __builtin_amdgcn_logf(x)

// DPP quad-perm reduces (VALU pipe): xor1 = 0xB1, xor2 = 0x4E
#define DPPF(v, c) __int_as_float(__builtin_amdgcn_update_dpp( \
    __float_as_int(v), __float_as_int(v), (c), 0xF, 0xF, false))
#define RED4_MAX(v)  { v = fmaxf(v, DPPF(v, 0xB1)); v = fmaxf(v, DPPF(v, 0x4E)); }
#define RED4_ADD(v)  { v = v + DPPF(v, 0xB1); v = v + DPPF(v, 0x4E); }

// force a float4 to stay resident (compiler cannot rematerialize past this)
#define KEEP4(v) asm volatile("" : "+v"(v.x), "+v"(v.y), "+v"(v.z), "+v"(v.w))

// Threefry-2x32, 20 rounds, exactly as JAX's threefry2x32 lowering.
__host__ __device__ __forceinline__ void tf2x32(uint32_t k0, uint32_t k1,
                                                uint32_t x0, uint32_t x1,
                                                uint32_t& o0, uint32_t& o1) {
  uint32_t ks2 = k0 ^ k1 ^ 0x1BD11BDAu;
  x0 += k0; x1 += k1;
#define TFR(r) { x0 += x1; x1 = (x1 << r) | (x1 >> (32 - r)); x1 ^= x0; }
  TFR(13) TFR(15) TFR(26) TFR(6)
  x0 += k1;  x1 += ks2 + 1u;
  TFR(17) TFR(29) TFR(16) TFR(24)
  x0 += ks2; x1 += k0 + 2u;
  TFR(13) TFR(15) TFR(26) TFR(6)
  x0 += k0;  x1 += k1 + 3u;
  TFR(17) TFR(29) TFR(16) TFR(24)
  x0 += k1;  x1 += ks2 + 4u;
  TFR(13) TFR(15) TFR(26) TFR(6)
  x0 += ks2; x1 += k0 + 5u;
#undef TFR
  o0 = x0; o1 = x1;
}

__device__ __forceinline__ uint32_t jax_bits(uint32_t k0, uint32_t k1, uint32_t p) {
  uint32_t a, b; tf2x32(k0, k1, 0u, p, a, b);   // partitionable: counter (0, p)
  return a ^ b;
}

// ============================ Kernel 1: Sinkhorn ============================
__global__ __launch_bounds__(NT) void cfm_ot_kernel(
    const float* __restrict__ x1g, const float* __restrict__ x0g,
    float* __restrict__ pp)
{
  extern __shared__ float sm[];
  float* Mn  = sm;                     // [160][160], -M*log2e/eps, pads NEG_BIG
  float* x1L = Mn + RPAD * CPAD;       // 456
  float* x0L = x1L + 456;              // 456
  float* phi = x0L + 456;              // 160, pads stay 0
  float* psi = phi + 160;              // 160, pads stay NEG_BIG
  float* red = psi + 160;              // 16
  float4* Mn4  = (float4*)Mn;          // row stride 40 float4
  float4* phi4 = (float4*)phi;
  float4* psi4 = (float4*)psi;

  const int b    = blockIdx.x;
  const int tid  = threadIdx.x;
  const int lane = tid & 63;
  const int wid  = tid >> 6;

  // ---- init ----
  {
    const float4 nb = make_float4(NEG_BIG, NEG_BIG, NEG_BIG, NEG_BIG);
    #pragma unroll
    for (int k = 0; k < 10; ++k) Mn4[tid + NT * k] = nb;   // 6400 = 640*10
  }
  if (tid < 450) {
    x1L[tid] = x1g[b * 450 + tid];
    x0L[tid] = x0g[b * 450 + tid];
  }
  if (tid < 160) { phi[tid] = 0.f; psi[tid] = NEG_BIG; }
  __syncthreads();

  // ---- squared distances D[i][j], track block max ----
  const int colD = tid >> 2;   // 0..159
  const int hD   = tid & 3;
  float lmax = 0.f;
  if (colD < N_) {
    const float a0 = x1L[colD * 3 + 0], a1 = x1L[colD * 3 + 1], a2 = x1L[colD * 3 + 2];
    #pragma unroll
    for (int k = 0; k < 38; ++k) {
      const int i = 38 * hD + k;
      if (i < N_) {
        const float dx = x0L[i * 3 + 0] - a0;
        const float dy = x0L[i * 3 + 1] - a1;
        const float dz = x0L[i * 3 + 2] - a2;
        const float d = fmaf(dz, dz, fmaf(dy, dy, dx * dx));
        Mn[i * CPAD + colD] = d;
        lmax = fmaxf(lmax, d);
      }
    }
  }
  #pragma unroll
  for (int off = 1; off < 64; off <<= 1) lmax = fmaxf(lmax, __shfl_xor(lmax, off));
  if (lane == 0) red[wid] = lmax;
  __syncthreads();
  if (tid == 0) {
    float m = red[0];
    #pragma unroll
    for (int w = 1; w < 10; ++w) m = fmaxf(m, red[w]);
    red[15] = -C1f / m;
  }
  __syncthreads();
  const float nsc = red[15];
  if (colD < N_) {
    #pragma unroll
    for (int k = 0; k < 38; ++k) {
      const int i = 38 * hD + k;
      if (i < N_) Mn[i * CPAD + colD] *= nsc;
    }
  }
  __syncthreads();

  // ---- register tiles (whole matrix resident, twice) ----
  const int jA = tid >> 2;
  const int qA = tid & 3;
  float4 ca[10], rb[10];
  {
    const int rbase = 40 * qA;
    #pragma unroll
    for (int k = 0; k < 10; ++k) {
      ca[k].x = Mn[(rbase + 4 * k + 0) * CPAD + jA];
      ca[k].y = Mn[(rbase + 4 * k + 1) * CPAD + jA];
      ca[k].z = Mn[(rbase + 4 * k + 2) * CPAD + jA];
      ca[k].w = Mn[(rbase + 4 * k + 3) * CPAD + jA];
      KEEP4(ca[k]);
    }
    #pragma unroll
    for (int k = 0; k < 10; ++k) {
      rb[k] = Mn4[jA * 40 + 10 * qA + k];
      KEEP4(rb[k]);
    }
  }
  const int pbase = 10 * qA;

  // ---- 100 Sinkhorn iterations, log2 domain ----
  for (int it = 0; it < 100; ++it) {
    // phase A: psi_j = C0 - LSE2_i(phi_i + Mn[i][j])
    {
      float4 tm[10];
      float m = NEG_BIG;
      #pragma unroll
      for (int k = 0; k < 10; ++k) {
        const float4 p = phi4[pbase + k];
        tm[k].x = ca[k].x + p.x; tm[k].y = ca[k].y + p.y;
        tm[k].z = ca[k].z + p.z; tm[k].w = ca[k].w + p.w;
        m = fmaxf(m, fmaxf(tm[k].x, tm[k].y));
        m = fmaxf(m, fmaxf(tm[k].z, tm[k].w));
      }
      RED4_MAX(m)
      float s0 = 0.f, s1 = 0.f;
      #pragma unroll
      for (int k = 0; k < 10; ++k) {
        s0 += EXP2R(tm[k].x - m) + EXP2R(tm[k].y - m);
        s1 += EXP2R(tm[k].z - m) + EXP2R(tm[k].w - m);
      }
      float s = s0 + s1;
      RED4_ADD(s)
      if (qA == 0 && jA < N_) psi[jA] = C0f - (m + LOG2R(s));
    }
    __syncthreads();

    // phase B: phi_i = C0 - LSE2_j(psi_j + Mn[i][j])
    {
      float4 tm[10];
      float m = NEG_BIG;
      #pragma unroll
      for (int k = 0; k < 10; ++k) {
        const float4 p = psi4[pbase + k];
        tm[k].x = rb[k].x + p.x; tm[k].y = rb[k].y + p.y;
        tm[k].z = rb[k].z + p.z; tm[k].w = rb[k].w + p.w;
        m = fmaxf(m, fmaxf(tm[k].x, tm[k].y));
        m = fmaxf(m, fmaxf(tm[k].z, tm[k].w));
      }
      RED4_MAX(m)
      float s0 = 0.f, s1 = 0.f;
      #pragma unroll
      for (int k = 0; k < 10; ++k) {
        s0 += EXP2R(tm[k].x - m) + EXP2R(tm[k].y - m);
        s1 += EXP2R(tm[k].z - m) + EXP2R(tm[k].w - m);
      }
      float s = s0 + s1;
      RED4_ADD(s)
      if (qA == 0 && jA < N_) phi[jA] = C0f - (m + LOG2R(s));
    }
    __syncthreads();
  }

  // ---- write potentials + scale for the sampling kernel ----
  if (tid < N_) {
    pp[b * PPS + tid]       = phi[tid];
    pp[b * PPS + 150 + tid] = psi[tid];
  }
  if (tid == 0) pp[b * PPS + 300] = nsc;
}

// ======================= Kernel 2: sampling + MLP loss ======================
__global__ __launch_bounds__(NT) void cfm_sample_kernel(
    const float* __restrict__ x1g, const float* __restrict__ maskg,
    const float* __restrict__ tg, const float* __restrict__ x0g,
    const float* __restrict__ epsg,
    const float* __restrict__ W1, const float* __restrict__ b1,
    const float* __restrict__ W2, const float* __restrict__ b2,
    const float* __restrict__ pp, float* __restrict__ partials,
    uint32_t kj0, uint32_t kj1, uint32_t k1r0, uint32_t k1r1,
    uint32_t k2r0, uint32_t k2r1)
{
  __shared__ float x1L[450], x0L[450], phiS[152], psiS[152], mskS[152];
  __shared__ float yu[150 * 9];   // per-n: y0,y1,y2,u0,u1,u2,mot (stride 9)
  __shared__ float red[16];
  __shared__ int   iselS[152];

  const int b    = blockIdx.x;
  const int tid  = threadIdx.x;
  const int lane = tid & 63;
  const int wid  = tid >> 6;

  if (tid < 450) {
    x1L[tid] = x1g[b * 450 + tid];
    x0L[tid] = x0g[b * 450 + tid];
  }
  if (tid < N_) {
    phiS[tid] = pp[b * PPS + tid];
    psiS[tid] = pp[b * PPS + 150 + tid];
    mskS[tid] = maskg[b * 150 + tid];
    // i = randint(ki,(B,N),0,150): ((hi%150)*(2^32%150) + lo%150) % 150
    const uint32_t p = (uint32_t)(b * N_ + tid);
    const uint32_t hb = jax_bits(k1r0, k1r1, p);
    const uint32_t lb = jax_bits(k2r0, k2r1, p);
    iselS[tid] = (int)(((hb % 150u) * 46u + (lb % 150u)) % 150u);
  }
  const float nsc = pp[b * PPS + 300];
  const float tb  = tg[b];
  __syncthreads();

  // ---- S1: gumbel argmax per sample (wave per n), store y/u/mot ----
  for (int n = wid; n < N_; n += 10) {
    const uint32_t p = (uint32_t)(b * N_ + n);
    const int isel = iselS[n];
    const float phi_i = phiS[isel];
    const float xi0 = x0L[isel * 3 + 0], xi1 = x0L[isel * 3 + 1], xi2 = x0L[isel * 3 + 2];

    float best = -1e30f; int bestk = 0x7fffffff;
    #pragma unroll
    for (int c2 = 0; c2 < 3; ++c2) {
      const int k = lane + 64 * c2;
      if (k < N_) {
        const uint32_t bits = jax_bits(kj0, kj1, p * 150u + (uint32_t)k);
        float u = __uint_as_float((bits >> 9) | 0x3F800000u) - 1.0f;
        u = fmaxf(u, 1.17549435e-38f);
        const float nlu = -LN2f * LOG2R(u);
        const float g = -LN2f * LOG2R(nlu);
        // Mn[isel][k] recomputed bit-identically: same fmaf chain, one multiply
        const float dx = xi0 - x1L[k * 3 + 0];
        const float dy = xi1 - x1L[k * 3 + 1];
        const float dz = xi2 - x1L[k * 3 + 2];
        const float d2 = fmaf(dz, dz, fmaf(dy, dy, dx * dx));
        const float val = fmaf(phi_i + psiS[k] + nsc * d2, LN2f, g);
        if (val > best || (val == best && k < bestk)) { best = val; bestk = k; }
      }
    }
    #pragma unroll
    for (int off = 1; off < 64; off <<= 1) {
      const float ov = __shfl_xor(best, off);
      const int   ok = __shfl_xor(bestk, off);
      if (ov > best || (ov == best && ok < bestk)) { best = ov; bestk = ok; }
    }
    if (lane == 0) {
      const int j = bestk;
      const float mot = mskS[j];
      const float q0 = x1L[j * 3 + 0], q1 = x1L[j * 3 + 1], q2 = x1L[j * 3 + 2];
      const float omt = 1.f - tb;
      yu[n * 9 + 0] = xi0 * tb + q0 * omt + SIGMAf * epsg[b * 450 + n * 3 + 0];
      yu[n * 9 + 1] = xi1 * tb + q1 * omt + SIGMAf * epsg[b * 450 + n * 3 + 1];
      yu[n * 9 + 2] = xi2 * tb + q2 * omt + SIGMAf * epsg[b * 450 + n * 3 + 2];
      yu[n * 9 + 3] = (xi0 - q0) * mot;
      yu[n * 9 + 4] = (xi1 - q1) * mot;
      yu[n * 9 + 5] = (xi2 - q2) * mot;
      yu[n * 9 + 6] = mot;
    }
  }
  __syncthreads();

  // ---- S2: MLP, lane = sample, hd loop uniform -> scalar W loads ----
  float loss = 0.f;
  if (wid < 3) {
    const int n = wid * 64 + lane;
    if (n < N_) {
      const float y0 = yu[n * 9 + 0], y1 = yu[n * 9 + 1], y2 = yu[n * 9 + 2];
      const float u0 = yu[n * 9 + 3], u1 = yu[n * 9 + 4], u2 = yu[n * 9 + 5];
      const float mot = yu[n * 9 + 6];
      float a0 = 0.f, a1 = 0.f, a2 = 0.f;
      #pragma unroll 4
      for (int hd = 0; hd < 512; ++hd) {
        float z = b1[hd];
        z = fmaf(y0, W1[hd],        z);
        z = fmaf(y1, W1[512 + hd],  z);
        z = fmaf(y2, W1[1024 + hd], z);
        z = fmaf(tb, W1[1536 + hd], z);
        const float zc = fmaf(0.044715f * z, z * z, z);
        const float e2 = EXP2R(-2.3022082062161855f * zc);
        const float ge = z * __builtin_amdgcn_rcpf(1.f + e2);
        a0 = fmaf(ge, W2[hd * 3 + 0], a0);
        a1 = fmaf(ge, W2[hd * 3 + 1], a1);
        a2 = fmaf(ge, W2[hd * 3 + 2], a2);
      }
      const float v0 = (a0 + b2[0]) * mot;
      const float v1 = (a1 + b2[1]) * mot;
      const float v2 = (a2 + b2[2]) * mot;
      const float d0 = v0 - u0, d1 = v1 - u1, d2 = v2 - u2;
      loss = fmaf(d2, d2, fmaf(d1, d1, d0 * d0));
    }
    #pragma unroll
    for (int off = 1; off < 64; off <<= 1) loss += __shfl_xor(loss, off);
    if (lane == 0) red[wid] = loss;
  }
  __syncthreads();
  if (tid == 0) partials[b] = red[0] + red[1] + red[2];
}

__global__ void cfm_reduce_kernel(const float* __restrict__ partials,
                                  float* __restrict__ out) {
  const int tid = threadIdx.x;   // 64 threads
  float s = 0.f;
  #pragma unroll
  for (int q = 0; q < 8; ++q) s += partials[tid + 64 * q];
  #pragma unroll
  for (int off = 1; off < 64; off <<= 1) s += __shfl_xor(s, off);
  if (tid == 0) out[0] = s * (1.0f / 230400.0f);
}

extern "C" void kernel_launch(void* const* d_in, const int* in_sizes, int n_in,
                              void* d_out, int out_size, void* d_ws, size_t ws_size,
                              hipStream_t stream) {
  (void)in_sizes; (void)n_in; (void)out_size; (void)ws_size;
  const float* x    = (const float*)d_in[0];
  const float* mask = (const float*)d_in[1];
  const float* t    = (const float*)d_in[2];
  const float* x0n  = (const float*)d_in[3];
  const float* epsn = (const float*)d_in[4];
  const float* W1   = (const float*)d_in[5];
  const float* b1   = (const float*)d_in[6];
  const float* W2   = (const float*)d_in[7];
  const float* b2   = (const float*)d_in[8];
  float* out = (float*)d_out;

  float* pp       = (float*)d_ws;              // 512 * 304 floats
  float* partials = pp + B_ * PPS;             // 512 floats

  uint32_t ki0, ki1, kj0, kj1, k1r0, k1r1, k2r0, k2r1;
  tf2x32(0u, 42u, 0u, 0u, ki0, ki1);
  tf2x32(0u, 42u, 0u, 1u, kj0, kj1);
  tf2x32(ki0, ki1, 0u, 0u, k1r0, k1r1);
  tf2x32(ki0, ki1, 0u, 1u, k2r0, k2r1);

  const int SMEM = (RPAD * CPAD + 456 + 456 + 160 + 160 + 16) * (int)sizeof(float);
  (void)hipFuncSetAttribute(reinterpret_cast<const void*>(cfm_ot_kernel),
                            hipFuncAttributeMaxDynamicSharedMemorySize, SMEM);
  cfm_ot_kernel<<<B_, NT, SMEM, stream>>>(x, x0n, pp);
  cfm_sample_kernel<<<B_, NT, 0, stream>>>(x, mask, t, x0n, epsn, W1, b1, W2, b2,
                                           pp, partials,
                                           kj0, kj1, k1r0, k1r1, k2r0, k2r1);
  cfm_reduce_kernel<<<1, 64, 0, stream>>>(partials, out);
}

// Round 6
// 335.187 us; speedup vs baseline: 3.6998x; 1.8050x over previous
//
#include <hip/hip_runtime.h>
#include <cstdint>

#define B_ 512
#define N_ 150
#define NT 640
#define PPS 152            // per-b: 150 psi (log2 units) + nsc
#define C1f 144.26950408889634f    // log2(e)/eps, eps=0.01
#define LN2f 0.69314718055994531f
#define SIGMAf 1.0e-4f
#define INV_N (1.0f/150.0f)

// raw hardware transcendentals (1-ULP v_exp_f32 / v_log_f32)
#define EXP2R(x) __builtin_amdgcn_exp2f(x)
#define LOG2R(x) __builtin_amdgcn_logf(x)

// DPP quad-perm reduces (VALU pipe): xor1 = 0xB1, xor2 = 0x4E
#define DPPF(v, c) __int_as_float(__builtin_amdgcn_update_dpp( \
    __float_as_int(v), __float_as_int(v), (c), 0xF, 0xF, false))
#define RED4_ADD(v)  { v = v + DPPF(v, 0xB1); v = v + DPPF(v, 0x4E); }

// force a float4 to stay resident
#define KEEP4(v) asm volatile("" : "+v"(v.x), "+v"(v.y), "+v"(v.z), "+v"(v.w))

// Threefry-2x32, 20 rounds, exactly as JAX's threefry2x32 lowering.
__host__ __device__ __forceinline__ void tf2x32(uint32_t k0, uint32_t k1,
                                                uint32_t x0, uint32_t x1,
                                                uint32_t& o0, uint32_t& o1) {
  uint32_t ks2 = k0 ^ k1 ^ 0x1BD11BDAu;
  x0 += k0; x1 += k1;
#define TFR(r) { x0 += x1; x1 = (x1 << r) | (x1 >> (32 - r)); x1 ^= x0; }
  TFR(13) TFR(15) TFR(26) TFR(6)
  x0 += k1;  x1 += ks2 + 1u;
  TFR(17) TFR(29) TFR(16) TFR(24)
  x0 += ks2; x1 += k0 + 2u;
  TFR(13) TFR(15) TFR(26) TFR(6)
  x0 += k0;  x1 += k1 + 3u;
  TFR(17) TFR(29) TFR(16) TFR(24)
  x0 += k1;  x1 += ks2 + 4u;
  TFR(13) TFR(15) TFR(26) TFR(6)
  x0 += ks2; x1 += k0 + 5u;
#undef TFR
  o0 = x0; o1 = x1;
}

__device__ __forceinline__ uint32_t jax_bits(uint32_t k0, uint32_t k1, uint32_t p) {
  uint32_t a, b; tf2x32(k0, k1, 0u, p, a, b);   // partitionable: counter (0, p)
  return a ^ b;
}

// ============ Kernel 1: Sinkhorn, scaled form w/ per-phase absorption ========
__global__ __launch_bounds__(NT, 3) void cfm_ot_kernel(
    const float* __restrict__ x1g, const float* __restrict__ x0g,
    float* __restrict__ pp)
{
  __shared__ float x1L[480], x0L[480];          // padded with zeros
  __shared__ float vhat[160], uhat[160], PsiL[160];
  __shared__ float red[16];
  float4* vhat4 = (float4*)vhat;
  float4* uhat4 = (float4*)uhat;

  const int b    = blockIdx.x;
  const int tid  = threadIdx.x;
  const int lane = tid & 63;
  const int wid  = tid >> 6;

  if (tid < 480) {
    x1L[tid] = (tid < 450) ? x1g[b * 450 + tid] : 0.f;
    x0L[tid] = (tid < 450) ? x0g[b * 450 + tid] : 0.f;
  }
  if (tid < 160) { vhat[tid] = 0.f; uhat[tid] = 0.f; PsiL[tid] = 0.f; }
  __syncthreads();

  const int jA    = tid >> 2;     // column (A-tile) / row (B-tile), 0..159
  const int qA    = tid & 3;
  const int rbase = 40 * qA;
  const int pbase = 10 * qA;      // float4 index base into vhat4/uhat4
  const bool act  = (jA < N_);

  // ---- distances into both tiles (registers), track max over A-tile ----
  float4 Ka[10], Kb[10];
  float lmax = 0.f;
  {
    const float cx = x1L[jA * 3 + 0], cy = x1L[jA * 3 + 1], cz = x1L[jA * 3 + 2];
    #pragma unroll
    for (int k = 0; k < 10; ++k) {
      float tmp[4];
      #pragma unroll
      for (int c = 0; c < 4; ++c) {
        const int row = rbase + 4 * k + c;
        const float dx = x0L[row * 3 + 0] - cx;
        const float dy = x0L[row * 3 + 1] - cy;
        const float dz = x0L[row * 3 + 2] - cz;
        float d = fmaf(dz, dz, fmaf(dy, dy, dx * dx));
        d = (act && row < N_) ? d : 0.f;
        lmax = fmaxf(lmax, d);
        tmp[c] = d;
      }
      Ka[k] = make_float4(tmp[0], tmp[1], tmp[2], tmp[3]);
    }
    const float rx = x0L[jA * 3 + 0], ry = x0L[jA * 3 + 1], rz = x0L[jA * 3 + 2];
    #pragma unroll
    for (int k = 0; k < 10; ++k) {
      float tmp[4];
      #pragma unroll
      for (int c = 0; c < 4; ++c) {
        const int col = rbase + 4 * k + c;
        const float dx = rx - x1L[col * 3 + 0];
        const float dy = ry - x1L[col * 3 + 1];
        const float dz = rz - x1L[col * 3 + 2];
        float d = fmaf(dz, dz, fmaf(dy, dy, dx * dx));
        tmp[c] = (act && col < N_) ? d : 0.f;
      }
      Kb[k] = make_float4(tmp[0], tmp[1], tmp[2], tmp[3]);
    }
  }
  #pragma unroll
  for (int off = 1; off < 64; off <<= 1) lmax = fmaxf(lmax, __shfl_xor(lmax, off));
  if (lane == 0) red[wid] = lmax;
  __syncthreads();
  if (tid == 0) {
    float m = red[0];
    #pragma unroll
    for (int w = 1; w < 10; ++w) m = fmaxf(m, red[w]);
    red[15] = -C1f / m;
  }
  __syncthreads();
  const float nsc = red[15];

  // ---- K = exp2(nsc * D); zero the pad entries (exp2(0)=1 must not leak) ----
  #pragma unroll
  for (int k = 0; k < 10; ++k) {
    float ta[4] = {Ka[k].x, Ka[k].y, Ka[k].z, Ka[k].w};
    float tb[4] = {Kb[k].x, Kb[k].y, Kb[k].z, Kb[k].w};
    #pragma unroll
    for (int c = 0; c < 4; ++c) {
      const int rc = rbase + 4 * k + c;
      const bool v = act && (rc < N_);
      ta[c] = v ? EXP2R(nsc * ta[c]) : 0.f;
      tb[c] = v ? EXP2R(nsc * tb[c]) : 0.f;
    }
    Ka[k] = make_float4(ta[0], ta[1], ta[2], ta[3]);
    Kb[k] = make_float4(tb[0], tb[1], tb[2], tb[3]);
    KEEP4(Ka[k]); KEEP4(Kb[k]);
  }

  // ---- 100 iterations: colsum->scale, rowsum->scale (absorb every phase) ----
  for (int it = 0; it < 100; ++it) {
    // phase A: s_j = sum_i K[i][j]; vhat = (1/N)/s; K *= vhat; Psi += log2
    {
      float4 s4 = Ka[0];
      #pragma unroll
      for (int k = 1; k < 10; ++k) {
        s4.x += Ka[k].x; s4.y += Ka[k].y; s4.z += Ka[k].z; s4.w += Ka[k].w;
      }
      float s = (s4.x + s4.y) + (s4.z + s4.w);
      RED4_ADD(s)
      if (qA == 0 && act) {
        const float vh = __builtin_amdgcn_rcpf(fmaxf(s, 1e-37f)) * INV_N;
        vhat[jA] = vh;
        PsiL[jA] += LOG2R(vh);
      }
    }
    __syncthreads();
    {
      const float vs = vhat[jA];
      #pragma unroll
      for (int k = 0; k < 10; ++k) {
        Ka[k].x *= vs; Ka[k].y *= vs; Ka[k].z *= vs; Ka[k].w *= vs;
      }
      #pragma unroll
      for (int k = 0; k < 10; ++k) {
        const float4 vv = vhat4[pbase + k];
        Kb[k].x *= vv.x; Kb[k].y *= vv.y; Kb[k].z *= vv.z; Kb[k].w *= vv.w;
      }
    }
    // phase B: s_i = sum_j K[i][j]; uhat = (1/N)/s; K *= uhat
    {
      float4 s4 = Kb[0];
      #pragma unroll
      for (int k = 1; k < 10; ++k) {
        s4.x += Kb[k].x; s4.y += Kb[k].y; s4.z += Kb[k].z; s4.w += Kb[k].w;
      }
      float s = (s4.x + s4.y) + (s4.z + s4.w);
      RED4_ADD(s)
      if (qA == 0 && act) {
        uhat[jA] = __builtin_amdgcn_rcpf(fmaxf(s, 1e-37f)) * INV_N;
      }
    }
    __syncthreads();
    {
      const float us = uhat[jA];
      #pragma unroll
      for (int k = 0; k < 10; ++k) {
        Kb[k].x *= us; Kb[k].y *= us; Kb[k].z *= us; Kb[k].w *= us;
      }
      #pragma unroll
      for (int k = 0; k < 10; ++k) {
        const float4 uu = uhat4[pbase + k];
        Ka[k].x *= uu.x; Ka[k].y *= uu.y; Ka[k].z *= uu.z; Ka[k].w *= uu.w;
      }
    }
  }

  // ---- write Psi (log2 units) + nsc; Phi not needed (row-shift invariant) ----
  if (tid < N_) pp[b * PPS + tid] = PsiL[tid];
  if (tid == 0) pp[b * PPS + 150] = nsc;
}

// ======================= Kernel 2: sampling + MLP loss ======================
__global__ __launch_bounds__(NT) void cfm_sample_kernel(
    const float* __restrict__ x1g, const float* __restrict__ maskg,
    const float* __restrict__ tg, const float* __restrict__ x0g,
    const float* __restrict__ epsg,
    const float* __restrict__ W1, const float* __restrict__ b1,
    const float* __restrict__ W2, const float* __restrict__ b2,
    const float* __restrict__ pp, float* __restrict__ partials,
    uint32_t kj0, uint32_t kj1, uint32_t k1r0, uint32_t k1r1,
    uint32_t k2r0, uint32_t k2r1)
{
  __shared__ float x1L[450], x0L[450], psiS[152], mskS[152];
  __shared__ float yu[150 * 9];   // per-n: y0,y1,y2,u0,u1,u2,mot (stride 9)
  __shared__ float red[16];
  __shared__ int   iselS[152];

  const int b    = blockIdx.x;
  const int tid  = threadIdx.x;
  const int lane = tid & 63;
  const int wid  = tid >> 6;

  if (tid < 450) {
    x1L[tid] = x1g[b * 450 + tid];
    x0L[tid] = x0g[b * 450 + tid];
  }
  if (tid < N_) {
    psiS[tid] = pp[b * PPS + tid];
    mskS[tid] = maskg[b * 150 + tid];
    // i = randint(ki,(B,N),0,150): ((hi%150)*(2^32%150) + lo%150) % 150
    const uint32_t p = (uint32_t)(b * N_ + tid);
    const uint32_t hb = jax_bits(k1r0, k1r1, p);
    const uint32_t lb = jax_bits(k2r0, k2r1, p);
    iselS[tid] = (int)(((hb % 150u) * 46u + (lb % 150u)) % 150u);
  }
  const float nsc = pp[b * PPS + 150];
  const float tb  = tg[b];
  __syncthreads();

  // ---- S1: gumbel argmax per sample (wave per n), store y/u/mot ----
  for (int n = wid; n < N_; n += 10) {
    const uint32_t p = (uint32_t)(b * N_ + n);
    const int isel = iselS[n];
    const float xi0 = x0L[isel * 3 + 0], xi1 = x0L[isel * 3 + 1], xi2 = x0L[isel * 3 + 2];

    float best = -1e30f; int bestk = 0x7fffffff;
    #pragma unroll
    for (int c2 = 0; c2 < 3; ++c2) {
      const int k = lane + 64 * c2;
      if (k < N_) {
        const uint32_t bits = jax_bits(kj0, kj1, p * 150u + (uint32_t)k);
        float u = __uint_as_float((bits >> 9) | 0x3F800000u) - 1.0f;
        u = fmaxf(u, 1.17549435e-38f);
        const float nlu = -LN2f * LOG2R(u);
        const float g = -LN2f * LOG2R(nlu);
        const float dx = xi0 - x1L[k * 3 + 0];
        const float dy = xi1 - x1L[k * 3 + 1];
        const float dz = xi2 - x1L[k * 3 + 2];
        const float d2 = fmaf(dz, dz, fmaf(dy, dy, dx * dx));
        const float val = fmaf(psiS[k] + nsc * d2, LN2f, g);  // phi_i dropped: const over k
        if (val > best || (val == best && k < bestk)) { best = val; bestk = k; }
      }
    }
    #pragma unroll
    for (int off = 1; off < 64; off <<= 1) {
      const float ov = __shfl_xor(best, off);
      const int   ok = __shfl_xor(bestk, off);
      if (ov > best || (ov == best && ok < bestk)) { best = ov; bestk = ok; }
    }
    if (lane == 0) {
      const int j = bestk;
      const float mot = mskS[j];
      const float q0 = x1L[j * 3 + 0], q1 = x1L[j * 3 + 1], q2 = x1L[j * 3 + 2];
      const float omt = 1.f - tb;
      yu[n * 9 + 0] = xi0 * tb + q0 * omt + SIGMAf * epsg[b * 450 + n * 3 + 0];
      yu[n * 9 + 1] = xi1 * tb + q1 * omt + SIGMAf * epsg[b * 450 + n * 3 + 1];
      yu[n * 9 + 2] = xi2 * tb + q2 * omt + SIGMAf * epsg[b * 450 + n * 3 + 2];
      yu[n * 9 + 3] = (xi0 - q0) * mot;
      yu[n * 9 + 4] = (xi1 - q1) * mot;
      yu[n * 9 + 5] = (xi2 - q2) * mot;
      yu[n * 9 + 6] = mot;
    }
  }
  __syncthreads();

  // ---- S2: MLP, lane = sample, hd loop uniform -> scalar W loads ----
  float loss = 0.f;
  if (wid < 3) {
    const int n = wid * 64 + lane;
    if (n < N_) {
      const float y0 = yu[n * 9 + 0], y1 = yu[n * 9 + 1], y2 = yu[n * 9 + 2];
      const float u0 = yu[n * 9 + 3], u1 = yu[n * 9 + 4], u2 = yu[n * 9 + 5];
      const float mot = yu[n * 9 + 6];
      float a0 = 0.f, a1 = 0.f, a2 = 0.f;
      #pragma unroll 4
      for (int hd = 0; hd < 512; ++hd) {
        float z = b1[hd];
        z = fmaf(y0, W1[hd],        z);
        z = fmaf(y1, W1[512 + hd],  z);
        z = fmaf(y2, W1[1024 + hd], z);
        z = fmaf(tb, W1[1536 + hd], z);
        const float zc = fmaf(0.044715f * z, z * z, z);
        const float e2 = EXP2R(-2.3022082062161855f * zc);
        const float ge = z * __builtin_amdgcn_rcpf(1.f + e2);
        a0 = fmaf(ge, W2[hd * 3 + 0], a0);
        a1 = fmaf(ge, W2[hd * 3 + 1], a1);
        a2 = fmaf(ge, W2[hd * 3 + 2], a2);
      }
      const float v0 = (a0 + b2[0]) * mot;
      const float v1 = (a1 + b2[1]) * mot;
      const float v2 = (a2 + b2[2]) * mot;
      const float d0 = v0 - u0, d1 = v1 - u1, d2 = v2 - u2;
      loss = fmaf(d2, d2, fmaf(d1, d1, d0 * d0));
    }
    #pragma unroll
    for (int off = 1; off < 64; off <<= 1) loss += __shfl_xor(loss, off);
    if (lane == 0) red[wid] = loss;
  }
  __syncthreads();
  if (tid == 0) partials[b] = red[0] + red[1] + red[2];
}

__global__ void cfm_reduce_kernel(const float* __restrict__ partials,
                                  float* __restrict__ out) {
  const int tid = threadIdx.x;   // 64 threads
  float s = 0.f;
  #pragma unroll
  for (int q = 0; q < 8; ++q) s += partials[tid + 64 * q];
  #pragma unroll
  for (int off = 1; off < 64; off <<= 1) s += __shfl_xor(s, off);
  if (tid == 0) out[0] = s * (1.0f / 230400.0f);
}

extern "C" void kernel_launch(void* const* d_in, const int* in_sizes, int n_in,
                              void* d_out, int out_size, void* d_ws, size_t ws_size,
                              hipStream_t stream) {
  (void)in_sizes; (void)n_in; (void)out_size; (void)ws_size;
  const float* x    = (const float*)d_in[0];
  const float* mask = (const float*)d_in[1];
  const float* t    = (const float*)d_in[2];
  const float* x0n  = (const float*)d_in[3];
  const float* epsn = (const float*)d_in[4];
  const float* W1   = (const float*)d_in[5];
  const float* b1   = (const float*)d_in[6];
  const float* W2   = (const float*)d_in[7];
  const float* b2   = (const float*)d_in[8];
  float* out = (float*)d_out;

  float* pp       = (float*)d_ws;              // 512 * 152 floats
  float* partials = pp + B_ * PPS;             // 512 floats

  uint32_t ki0, ki1, kj0, kj1, k1r0, k1r1, k2r0, k2r1;
  tf2x32(0u, 42u, 0u, 0u, ki0, ki1);
  tf2x32(0u, 42u, 0u, 1u, kj0, kj1);
  tf2x32(ki0, ki1, 0u, 0u, k1r0, k1r1);
  tf2x32(ki0, ki1, 0u, 1u, k2r0, k2r1);

  cfm_ot_kernel<<<B_, NT, 0, stream>>>(x, x0n, pp);
  cfm_sample_kernel<<<B_, NT, 0, stream>>>(x, mask, t, x0n, epsn, W1, b1, W2, b2,
                                           pp, partials,
                                           kj0, kj1, k1r0, k1r1, k2r0, k2r1);
  cfm_reduce_kernel<<<1, 64, 0, stream>>>(partials, out);
}

// Round 7
// 314.802 us; speedup vs baseline: 3.9393x; 1.0648x over previous
//
#include <hip/hip_runtime.h>
#include <cstdint>

#define B_ 512
#define N_ 150
#define NT 640
#define PPS 152            // per-b: 150 psi (log2 units) + nsc
#define C1f 144.26950408889634f    // log2(e)/eps, eps=0.01
#define LN2f 0.69314718055994531f
#define SIGMAf 1.0e-4f
#define INV_N (1.0f/150.0f)

// raw hardware transcendentals (1-ULP v_exp_f32 / v_log_f32)
#define EXP2R(x) __builtin_amdgcn_exp2f(x)
#define LOG2R(x) __builtin_amdgcn_logf(x)

// DPP quad-perm reduces (VALU pipe): xor1 = 0xB1, xor2 = 0x4E
#define DPPF(v, c) __int_as_float(__builtin_amdgcn_update_dpp( \
    __float_as_int(v), __float_as_int(v), (c), 0xF, 0xF, false))
#define RED4_ADD(v)  { v = v + DPPF(v, 0xB1); v = v + DPPF(v, 0x4E); }

// Threefry-2x32, 20 rounds, exactly as JAX's threefry2x32 lowering.
__host__ __device__ __forceinline__ void tf2x32(uint32_t k0, uint32_t k1,
                                                uint32_t x0, uint32_t x1,
                                                uint32_t& o0, uint32_t& o1) {
  uint32_t ks2 = k0 ^ k1 ^ 0x1BD11BDAu;
  x0 += k0; x1 += k1;
#define TFR(r) { x0 += x1; x1 = (x1 << r) | (x1 >> (32 - r)); x1 ^= x0; }
  TFR(13) TFR(15) TFR(26) TFR(6)
  x0 += k1;  x1 += ks2 + 1u;
  TFR(17) TFR(29) TFR(16) TFR(24)
  x0 += ks2; x1 += k0 + 2u;
  TFR(13) TFR(15) TFR(26) TFR(6)
  x0 += k0;  x1 += k1 + 3u;
  TFR(17) TFR(29) TFR(16) TFR(24)
  x0 += k1;  x1 += ks2 + 4u;
  TFR(13) TFR(15) TFR(26) TFR(6)
  x0 += ks2; x1 += k0 + 5u;
#undef TFR
  o0 = x0; o1 = x1;
}

__device__ __forceinline__ uint32_t jax_bits(uint32_t k0, uint32_t k1, uint32_t p) {
  uint32_t a, b; tf2x32(k0, k1, 0u, p, a, b);   // partitionable: counter (0, p)
  return a ^ b;
}

// ==== Kernel 1: Sinkhorn, scaled form, ONE matrix copy (10x4 subtiles) ======
// thread (rg = tid/40, cg = tid%40) owns rows rg*10..+9, cols cg*4..+3.
__global__ __launch_bounds__(NT, 5) void cfm_ot_kernel(
    const float* __restrict__ x1g, const float* __restrict__ x0g,
    float* __restrict__ pp)
{
  __shared__ float x1L[480], x0L[480];
  __shared__ __align__(16) float colp[16 * 164];   // [rg][164] col partials
  __shared__ float rowq[160 * 11];                 // [row][11] quad row partials
  __shared__ __align__(16) float vhat[160];
  __shared__ float uhat[160], PsiL[160];
  __shared__ float red[16];
  float4* colp4 = (float4*)colp;    // row stride 41
  float4* vhat4 = (float4*)vhat;

  const int b    = blockIdx.x;
  const int tid  = threadIdx.x;
  const int lane = tid & 63;
  const int wid  = tid >> 6;
  const int rg   = tid / 40;        // 0..15
  const int cg   = tid - rg * 40;   // 0..39
  const int q    = tid & 3;         // == cg&3 (40 % 4 == 0)
  const int cgq  = cg >> 2;         // 0..9
  const int rbase = rg * 10;
  const int cbase = cg * 4;

  if (tid < 480) {
    x1L[tid] = (tid < 450) ? x1g[b * 450 + tid] : 0.f;
    x0L[tid] = (tid < 450) ? x0g[b * 450 + tid] : 0.f;
  }
  if (tid < 160) PsiL[tid] = 0.f;
  __syncthreads();

  // ---- distances, track block max ----
  float4 kt[10];
  float lmax = 0.f;
  {
    const float c0 = x1L[cbase * 3 + 0], c1 = x1L[cbase * 3 + 1], c2 = x1L[cbase * 3 + 2];
    const float d0 = x1L[cbase * 3 + 3], d1 = x1L[cbase * 3 + 4], d2 = x1L[cbase * 3 + 5];
    const float e0 = x1L[cbase * 3 + 6], e1 = x1L[cbase * 3 + 7], e2 = x1L[cbase * 3 + 8];
    const float f0 = x1L[cbase * 3 + 9], f1 = x1L[cbase * 3 + 10], f2 = x1L[cbase * 3 + 11];
    #pragma unroll
    for (int r = 0; r < 10; ++r) {
      const int row = rbase + r;
      const float rx = x0L[row * 3 + 0], ry = x0L[row * 3 + 1], rz = x0L[row * 3 + 2];
      float dx, dy, dz, d;
      dx = rx - c0; dy = ry - c1; dz = rz - c2;
      d = fmaf(dz, dz, fmaf(dy, dy, dx * dx));
      kt[r].x = (row < N_ && cbase + 0 < N_) ? d : 0.f;
      dx = rx - d0; dy = ry - d1; dz = rz - d2;
      d = fmaf(dz, dz, fmaf(dy, dy, dx * dx));
      kt[r].y = (row < N_ && cbase + 1 < N_) ? d : 0.f;
      dx = rx - e0; dy = ry - e1; dz = rz - e2;
      d = fmaf(dz, dz, fmaf(dy, dy, dx * dx));
      kt[r].z = (row < N_ && cbase + 2 < N_) ? d : 0.f;
      dx = rx - f0; dy = ry - f1; dz = rz - f2;
      d = fmaf(dz, dz, fmaf(dy, dy, dx * dx));
      kt[r].w = (row < N_ && cbase + 3 < N_) ? d : 0.f;
      lmax = fmaxf(lmax, fmaxf(fmaxf(kt[r].x, kt[r].y), fmaxf(kt[r].z, kt[r].w)));
    }
  }
  #pragma unroll
  for (int off = 1; off < 64; off <<= 1) lmax = fmaxf(lmax, __shfl_xor(lmax, off));
  if (lane == 0) red[wid] = lmax;
  __syncthreads();
  if (tid == 0) {
    float m = red[0];
    #pragma unroll
    for (int w = 1; w < 10; ++w) m = fmaxf(m, red[w]);
    red[15] = -C1f / m;
  }
  __syncthreads();
  const float nsc = red[15];

  // ---- K = exp2(nsc * D); pads (d==0 entries from masking) -> 0 ----
  #pragma unroll
  for (int r = 0; r < 10; ++r) {
    const int row = rbase + r;
    float t[4] = {kt[r].x, kt[r].y, kt[r].z, kt[r].w};
    #pragma unroll
    for (int c = 0; c < 4; ++c) {
      const bool v = (row < N_) && (cbase + c < N_);
      t[c] = v ? EXP2R(nsc * t[c]) : 0.f;
    }
    kt[r] = make_float4(t[0], t[1], t[2], t[3]);
  }

  // ---- 100 iterations ----
  for (int it = 0; it < 100; ++it) {
    // (1) col partials: sum over my 10 rows
    {
      float4 p4 = kt[0];
      #pragma unroll
      for (int r = 1; r < 10; ++r) {
        p4.x += kt[r].x; p4.y += kt[r].y; p4.z += kt[r].z; p4.w += kt[r].w;
      }
      colp4[rg * 41 + cg] = p4;
    }
    __syncthreads();
    // (3) finalize colsum -> vhat, accumulate Psi
    if (tid < 160) {
      float s = 0.f;
      #pragma unroll
      for (int k = 0; k < 16; ++k) s += colp[k * 164 + tid];
      const float vh = __builtin_amdgcn_rcpf(fmaxf(s, 1e-37f)) * INV_N;
      vhat[tid] = vh;
      if (tid < N_) PsiL[tid] += LOG2R(vh);
    }
    __syncthreads();
    // (5) scale cols by vhat; row partials via quad reduce (16 cols/quad)
    {
      const float4 vv = vhat4[cg];
      #pragma unroll
      for (int r = 0; r < 10; ++r) {
        kt[r].x *= vv.x; kt[r].y *= vv.y; kt[r].z *= vv.z; kt[r].w *= vv.w;
        float rp = (kt[r].x + kt[r].y) + (kt[r].z + kt[r].w);
        RED4_ADD(rp)
        if (q == 0) rowq[(rbase + r) * 11 + cgq] = rp;
      }
    }
    __syncthreads();
    // (7) finalize rowsum -> uhat
    if (tid < 160) {
      float s = 0.f;
      #pragma unroll
      for (int u = 0; u < 10; ++u) s += rowq[tid * 11 + u];
      uhat[tid] = __builtin_amdgcn_rcpf(fmaxf(s, 1e-37f)) * INV_N;
    }
    __syncthreads();
    // (9) scale rows by uhat (broadcast reads)
    #pragma unroll
    for (int r = 0; r < 10; ++r) {
      const float us = uhat[rbase + r];
      kt[r].x *= us; kt[r].y *= us; kt[r].z *= us; kt[r].w *= us;
    }
  }

  // ---- write Psi (log2 units) + nsc ----
  if (tid < N_) pp[b * PPS + tid] = PsiL[tid];
  if (tid == 0) pp[b * PPS + 150] = nsc;
}

// ======================= Kernel 2: sampling + MLP loss ======================
__global__ __launch_bounds__(NT) void cfm_sample_kernel(
    const float* __restrict__ x1g, const float* __restrict__ maskg,
    const float* __restrict__ tg, const float* __restrict__ x0g,
    const float* __restrict__ epsg,
    const float* __restrict__ W1, const float* __restrict__ b1,
    const float* __restrict__ W2, const float* __restrict__ b2,
    const float* __restrict__ pp, float* __restrict__ partials,
    uint32_t kj0, uint32_t kj1, uint32_t k1r0, uint32_t k1r1,
    uint32_t k2r0, uint32_t k2r1)
{
  __shared__ float x1L[450], x0L[450], psiS[152], mskS[152];
  __shared__ float yu[150 * 9];   // per-n: y0,y1,y2,u0,u1,u2,mot (stride 9)
  __shared__ float red[16];
  __shared__ int   iselS[152];

  const int b    = blockIdx.x;
  const int tid  = threadIdx.x;
  const int lane = tid & 63;
  const int wid  = tid >> 6;

  if (tid < 450) {
    x1L[tid] = x1g[b * 450 + tid];
    x0L[tid] = x0g[b * 450 + tid];
  }
  if (tid < N_) {
    psiS[tid] = pp[b * PPS + tid];
    mskS[tid] = maskg[b * 150 + tid];
    // i = randint(ki,(B,N),0,150): ((hi%150)*(2^32%150) + lo%150) % 150
    const uint32_t p = (uint32_t)(b * N_ + tid);
    const uint32_t hb = jax_bits(k1r0, k1r1, p);
    const uint32_t lb = jax_bits(k2r0, k2r1, p);
    iselS[tid] = (int)(((hb % 150u) * 46u + (lb % 150u)) % 150u);
  }
  const float nsc = pp[b * PPS + 150];
  const float tb  = tg[b];
  __syncthreads();

  // ---- S1: gumbel argmax per sample (wave per n), store y/u/mot ----
  for (int n = wid; n < N_; n += 10) {
    const uint32_t p = (uint32_t)(b * N_ + n);
    const int isel = iselS[n];
    const float xi0 = x0L[isel * 3 + 0], xi1 = x0L[isel * 3 + 1], xi2 = x0L[isel * 3 + 2];

    float best = -1e30f; int bestk = 0x7fffffff;
    #pragma unroll
    for (int c2 = 0; c2 < 3; ++c2) {
      const int k = lane + 64 * c2;
      if (k < N_) {
        const uint32_t bits = jax_bits(kj0, kj1, p * 150u + (uint32_t)k);
        float u = __uint_as_float((bits >> 9) | 0x3F800000u) - 1.0f;
        u = fmaxf(u, 1.17549435e-38f);
        const float nlu = -LN2f * LOG2R(u);
        const float g = -LN2f * LOG2R(nlu);
        const float dx = xi0 - x1L[k * 3 + 0];
        const float dy = xi1 - x1L[k * 3 + 1];
        const float dz = xi2 - x1L[k * 3 + 2];
        const float d2 = fmaf(dz, dz, fmaf(dy, dy, dx * dx));
        const float val = fmaf(psiS[k] + nsc * d2, LN2f, g);  // phi_i const over k
        if (val > best || (val == best && k < bestk)) { best = val; bestk = k; }
      }
    }
    #pragma unroll
    for (int off = 1; off < 64; off <<= 1) {
      const float ov = __shfl_xor(best, off);
      const int   ok = __shfl_xor(bestk, off);
      if (ov > best || (ov == best && ok < bestk)) { best = ov; bestk = ok; }
    }
    if (lane == 0) {
      const int j = bestk;
      const float mot = mskS[j];
      const float q0 = x1L[j * 3 + 0], q1 = x1L[j * 3 + 1], q2 = x1L[j * 3 + 2];
      const float omt = 1.f - tb;
      yu[n * 9 + 0] = xi0 * tb + q0 * omt + SIGMAf * epsg[b * 450 + n * 3 + 0];
      yu[n * 9 + 1] = xi1 * tb + q1 * omt + SIGMAf * epsg[b * 450 + n * 3 + 1];
      yu[n * 9 + 2] = xi2 * tb + q2 * omt + SIGMAf * epsg[b * 450 + n * 3 + 2];
      yu[n * 9 + 3] = (xi0 - q0) * mot;
      yu[n * 9 + 4] = (xi1 - q1) * mot;
      yu[n * 9 + 5] = (xi2 - q2) * mot;
      yu[n * 9 + 6] = mot;
    }
  }
  __syncthreads();

  // ---- S2: MLP, lane = sample, hd loop uniform -> scalar W loads ----
  float loss = 0.f;
  if (wid < 3) {
    const int n = wid * 64 + lane;
    if (n < N_) {
      const float y0 = yu[n * 9 + 0], y1 = yu[n * 9 + 1], y2 = yu[n * 9 + 2];
      const float u0 = yu[n * 9 + 3], u1 = yu[n * 9 + 4], u2 = yu[n * 9 + 5];
      const float mot = yu[n * 9 + 6];
      float a0 = 0.f, a1 = 0.f, a2 = 0.f;
      #pragma unroll 4
      for (int hd = 0; hd < 512; ++hd) {
        float z = b1[hd];
        z = fmaf(y0, W1[hd],        z);
        z = fmaf(y1, W1[512 + hd],  z);
        z = fmaf(y2, W1[1024 + hd], z);
        z = fmaf(tb, W1[1536 + hd], z);
        const float zc = fmaf(0.044715f * z, z * z, z);
        const float e2 = EXP2R(-2.3022082062161855f * zc);
        const float ge = z * __builtin_amdgcn_rcpf(1.f + e2);
        a0 = fmaf(ge, W2[hd * 3 + 0], a0);
        a1 = fmaf(ge, W2[hd * 3 + 1], a1);
        a2 = fmaf(ge, W2[hd * 3 + 2], a2);
      }
      const float v0 = (a0 + b2[0]) * mot;
      const float v1 = (a1 + b2[1]) * mot;
      const float v2 = (a2 + b2[2]) * mot;
      const float d0 = v0 - u0, d1 = v1 - u1, d2 = v2 - u2;
      loss = fmaf(d2, d2, fmaf(d1, d1, d0 * d0));
    }
    #pragma unroll
    for (int off = 1; off < 64; off <<= 1) loss += __shfl_xor(loss, off);
    if (lane == 0) red[wid] = loss;
  }
  __syncthreads();
  if (tid == 0) partials[b] = red[0] + red[1] + red[2];
}

__global__ void cfm_reduce_kernel(const float* __restrict__ partials,
                                  float* __restrict__ out) {
  const int tid = threadIdx.x;   // 64 threads
  float s = 0.f;
  #pragma unroll
  for (int q = 0; q < 8; ++q) s += partials[tid + 64 * q];
  #pragma unroll
  for (int off = 1; off < 64; off <<= 1) s += __shfl_xor(s, off);
  if (tid == 0) out[0] = s * (1.0f / 230400.0f);
}

extern "C" void kernel_launch(void* const* d_in, const int* in_sizes, int n_in,
                              void* d_out, int out_size, void* d_ws, size_t ws_size,
                              hipStream_t stream) {
  (void)in_sizes; (void)n_in; (void)out_size; (void)ws_size;
  const float* x    = (const float*)d_in[0];
  const float* mask = (const float*)d_in[1];
  const float* t    = (const float*)d_in[2];
  const float* x0n  = (const float*)d_in[3];
  const float* epsn = (const float*)d_in[4];
  const float* W1   = (const float*)d_in[5];
  const float* b1   = (const float*)d_in[6];
  const float* W2   = (const float*)d_in[7];
  const float* b2   = (const float*)d_in[8];
  float* out = (float*)d_out;

  float* pp       = (float*)d_ws;              // 512 * 152 floats
  float* partials = pp + B_ * PPS;             // 512 floats

  uint32_t ki0, ki1, kj0, kj1, k1r0, k1r1, k2r0, k2r1;
  tf2x32(0u, 42u, 0u, 0u, ki0, ki1);
  tf2x32(0u, 42u, 0u, 1u, kj0, kj1);
  tf2x32(ki0, ki1, 0u, 0u, k1r0, k1r1);
  tf2x32(ki0, ki1, 0u, 1u, k2r0, k2r1);

  cfm_ot_kernel<<<B_, NT, 0, stream>>>(x, x0n, pp);
  cfm_sample_kernel<<<B_, NT, 0, stream>>>(x, mask, t, x0n, epsn, W1, b1, W2, b2,
                                           pp, partials,
                                           kj0, kj1, k1r0, k1r1, k2r0, k2r1);
  cfm_reduce_kernel<<<1, 64, 0, stream>>>(partials, out);
}

// Round 8
// 270.048 us; speedup vs baseline: 4.5922x; 1.1657x over previous
//
#include <hip/hip_runtime.h>
#include <cstdint>

#define B_ 512
#define N_ 150
#define NT 640
#define PPS 152            // per-b: 150 psi (log2 units) + nsc
#define C1f 144.26950408889634f    // log2(e)/eps, eps=0.01
#define LN2f 0.69314718055994531f
#define SIGMAf 1.0e-4f
#define INV_N (1.0f/150.0f)

// raw hardware transcendentals (1-ULP v_exp_f32 / v_log_f32)
#define EXP2R(x) __builtin_amdgcn_exp2f(x)
#define LOG2R(x) __builtin_amdgcn_logf(x)

// DPP quad-perm reduces (VALU pipe): xor1 = 0xB1, xor2 = 0x4E
#define DPPF(v, c) __int_as_float(__builtin_amdgcn_update_dpp( \
    __float_as_int(v), __float_as_int(v), (c), 0xF, 0xF, false))
#define RED4_ADD(v)  { v = v + DPPF(v, 0xB1); v = v + DPPF(v, 0x4E); }

// Threefry-2x32, 20 rounds, exactly as JAX's threefry2x32 lowering.
__host__ __device__ __forceinline__ void tf2x32(uint32_t k0, uint32_t k1,
                                                uint32_t x0, uint32_t x1,
                                                uint32_t& o0, uint32_t& o1) {
  uint32_t ks2 = k0 ^ k1 ^ 0x1BD11BDAu;
  x0 += k0; x1 += k1;
#define TFR(r) { x0 += x1; x1 = (x1 << r) | (x1 >> (32 - r)); x1 ^= x0; }
  TFR(13) TFR(15) TFR(26) TFR(6)
  x0 += k1;  x1 += ks2 + 1u;
  TFR(17) TFR(29) TFR(16) TFR(24)
  x0 += ks2; x1 += k0 + 2u;
  TFR(13) TFR(15) TFR(26) TFR(6)
  x0 += k0;  x1 += k1 + 3u;
  TFR(17) TFR(29) TFR(16) TFR(24)
  x0 += k1;  x1 += ks2 + 4u;
  TFR(13) TFR(15) TFR(26) TFR(6)
  x0 += ks2; x1 += k0 + 5u;
#undef TFR
  o0 = x0; o1 = x1;
}

__device__ __forceinline__ uint32_t jax_bits(uint32_t k0, uint32_t k1, uint32_t p) {
  uint32_t a, b; tf2x32(k0, k1, 0u, p, a, b);   // partitionable: counter (0, p)
  return a ^ b;
}

// ==== Kernel 1: Sinkhorn, classic scaled form: K static, iterate u/v =======
// thread (rg = tid/40, cg = tid%40) owns rows rg*10..+9, cols cg*4..+3.
// v_j = (1/N)/sum_i K_ij u_i ;  u_i = (1/N)/sum_j K_ij v_j ;  psi = log2(v).
__global__ __launch_bounds__(NT, 5) void cfm_ot_kernel(
    const float* __restrict__ x1g, const float* __restrict__ x0g,
    float* __restrict__ pp)
{
  __shared__ float x1L[480], x0L[480];
  __shared__ __align__(16) float colp[16 * 164];   // [rg][164] col partials
  __shared__ float rowq[160 * 11];                 // [row][11] quad row partials
  __shared__ __align__(16) float vhat[160];        // v
  __shared__ float uhat[160];                      // u
  __shared__ float red[16];
  float4* colp4 = (float4*)colp;    // row stride 41
  float4* vhat4 = (float4*)vhat;

  const int b    = blockIdx.x;
  const int tid  = threadIdx.x;
  const int lane = tid & 63;
  const int wid  = tid >> 6;
  const int rg   = tid / 40;        // 0..15
  const int cg   = tid - rg * 40;   // 0..39
  const int q    = tid & 3;         // == cg&3 (40 % 4 == 0)
  const int cgq  = cg >> 2;         // 0..9
  const int rbase = rg * 10;
  const int cbase = cg * 4;

  if (tid < 480) {
    x1L[tid] = (tid < 450) ? x1g[b * 450 + tid] : 0.f;
    x0L[tid] = (tid < 450) ? x0g[b * 450 + tid] : 0.f;
  }
  __syncthreads();

  // ---- distances, track block max ----
  float4 kt[10];
  float lmax = 0.f;
  {
    const float c0 = x1L[cbase * 3 + 0], c1 = x1L[cbase * 3 + 1], c2 = x1L[cbase * 3 + 2];
    const float d0 = x1L[cbase * 3 + 3], d1 = x1L[cbase * 3 + 4], d2 = x1L[cbase * 3 + 5];
    const float e0 = x1L[cbase * 3 + 6], e1 = x1L[cbase * 3 + 7], e2 = x1L[cbase * 3 + 8];
    const float f0 = x1L[cbase * 3 + 9], f1 = x1L[cbase * 3 + 10], f2 = x1L[cbase * 3 + 11];
    #pragma unroll
    for (int r = 0; r < 10; ++r) {
      const int row = rbase + r;
      const float rx = x0L[row * 3 + 0], ry = x0L[row * 3 + 1], rz = x0L[row * 3 + 2];
      float dx, dy, dz, d;
      dx = rx - c0; dy = ry - c1; dz = rz - c2;
      d = fmaf(dz, dz, fmaf(dy, dy, dx * dx));
      kt[r].x = (row < N_ && cbase + 0 < N_) ? d : 0.f;
      dx = rx - d0; dy = ry - d1; dz = rz - d2;
      d = fmaf(dz, dz, fmaf(dy, dy, dx * dx));
      kt[r].y = (row < N_ && cbase + 1 < N_) ? d : 0.f;
      dx = rx - e0; dy = ry - e1; dz = rz - e2;
      d = fmaf(dz, dz, fmaf(dy, dy, dx * dx));
      kt[r].z = (row < N_ && cbase + 2 < N_) ? d : 0.f;
      dx = rx - f0; dy = ry - f1; dz = rz - f2;
      d = fmaf(dz, dz, fmaf(dy, dy, dx * dx));
      kt[r].w = (row < N_ && cbase + 3 < N_) ? d : 0.f;
      lmax = fmaxf(lmax, fmaxf(fmaxf(kt[r].x, kt[r].y), fmaxf(kt[r].z, kt[r].w)));
    }
  }
  #pragma unroll
  for (int off = 1; off < 64; off <<= 1) lmax = fmaxf(lmax, __shfl_xor(lmax, off));
  if (lane == 0) red[wid] = lmax;
  if (tid < 160) uhat[tid] = 1.0f;        // u0 = 1 (f = 0)
  __syncthreads();
  if (tid == 0) {
    float m = red[0];
    #pragma unroll
    for (int w = 1; w < 10; ++w) m = fmaxf(m, red[w]);
    red[15] = -C1f / m;
  }
  __syncthreads();
  const float nsc = red[15];

  // ---- K = exp2(nsc * D); pads -> 0 ----
  #pragma unroll
  for (int r = 0; r < 10; ++r) {
    const int row = rbase + r;
    float t[4] = {kt[r].x, kt[r].y, kt[r].z, kt[r].w};
    #pragma unroll
    for (int c = 0; c < 4; ++c) {
      const bool v = (row < N_) && (cbase + c < N_);
      t[c] = v ? EXP2R(nsc * t[c]) : 0.f;
    }
    kt[r] = make_float4(t[0], t[1], t[2], t[3]);
  }

  // ---- 100 iterations; K read-only, only u/v updated ----
  for (int it = 0; it < 100; ++it) {
    // phase A: col partials of K^T u  (u broadcast per row)
    {
      float4 p4 = make_float4(0.f, 0.f, 0.f, 0.f);
      #pragma unroll
      for (int r = 0; r < 10; ++r) {
        const float ur = uhat[rbase + r];
        p4.x = fmaf(kt[r].x, ur, p4.x);
        p4.y = fmaf(kt[r].y, ur, p4.y);
        p4.z = fmaf(kt[r].z, ur, p4.z);
        p4.w = fmaf(kt[r].w, ur, p4.w);
      }
      colp4[rg * 41 + cg] = p4;
    }
    __syncthreads();
    if (tid < 160) {
      float s = 0.f;
      #pragma unroll
      for (int k = 0; k < 16; ++k) s += colp[k * 164 + tid];
      vhat[tid] = __builtin_amdgcn_rcpf(fmaxf(s, 1e-37f)) * INV_N;
    }
    __syncthreads();
    // phase B: row partials of K v  (v = my 4 columns, one b128 read)
    {
      const float4 vv = vhat4[cg];
      #pragma unroll
      for (int r = 0; r < 10; ++r) {
        float rp = kt[r].x * vv.x;
        rp = fmaf(kt[r].y, vv.y, rp);
        rp = fmaf(kt[r].z, vv.z, rp);
        rp = fmaf(kt[r].w, vv.w, rp);
        RED4_ADD(rp)
        if (q == 0) rowq[(rbase + r) * 11 + cgq] = rp;
      }
    }
    __syncthreads();
    if (tid < 160) {
      float s = 0.f;
      #pragma unroll
      for (int u = 0; u < 10; ++u) s += rowq[tid * 11 + u];
      uhat[tid] = __builtin_amdgcn_rcpf(fmaxf(s, 1e-37f)) * INV_N;
    }
    __syncthreads();
  }

  // ---- psi = log2(v_final) + nsc ----
  if (tid < N_) pp[b * PPS + tid] = LOG2R(vhat[tid]);
  if (tid == 0) pp[b * PPS + 150] = nsc;
}

// ======================= Kernel 2: sampling + MLP loss ======================
__global__ __launch_bounds__(NT) void cfm_sample_kernel(
    const float* __restrict__ x1g, const float* __restrict__ maskg,
    const float* __restrict__ tg, const float* __restrict__ x0g,
    const float* __restrict__ epsg,
    const float* __restrict__ W1, const float* __restrict__ b1,
    const float* __restrict__ W2, const float* __restrict__ b2,
    const float* __restrict__ pp, float* __restrict__ partials,
    uint32_t kj0, uint32_t kj1, uint32_t k1r0, uint32_t k1r1,
    uint32_t k2r0, uint32_t k2r1)
{
  __shared__ float x1L[450], x0L[450], psiS[152], mskS[152];
  __shared__ float yu[150 * 9];   // per-n: y0,y1,y2,u0,u1,u2,mot (stride 9)
  __shared__ float red[16];
  __shared__ int   iselS[152];

  const int b    = blockIdx.x;
  const int tid  = threadIdx.x;
  const int lane = tid & 63;
  const int wid  = tid >> 6;

  if (tid < 450) {
    x1L[tid] = x1g[b * 450 + tid];
    x0L[tid] = x0g[b * 450 + tid];
  }
  if (tid < N_) {
    psiS[tid] = pp[b * PPS + tid];
    mskS[tid] = maskg[b * 150 + tid];
    // i = randint(ki,(B,N),0,150): ((hi%150)*(2^32%150) + lo%150) % 150
    const uint32_t p = (uint32_t)(b * N_ + tid);
    const uint32_t hb = jax_bits(k1r0, k1r1, p);
    const uint32_t lb = jax_bits(k2r0, k2r1, p);
    iselS[tid] = (int)(((hb % 150u) * 46u + (lb % 150u)) % 150u);
  }
  const float nsc = pp[b * PPS + 150];
  const float tb  = tg[b];
  __syncthreads();

  // ---- S1: gumbel argmax per sample (wave per n), store y/u/mot ----
  for (int n = wid; n < N_; n += 10) {
    const uint32_t p = (uint32_t)(b * N_ + n);
    const int isel = iselS[n];
    const float xi0 = x0L[isel * 3 + 0], xi1 = x0L[isel * 3 + 1], xi2 = x0L[isel * 3 + 2];

    float best = -1e30f; int bestk = 0x7fffffff;
    #pragma unroll
    for (int c2 = 0; c2 < 3; ++c2) {
      const int k = lane + 64 * c2;
      if (k < N_) {
        const uint32_t bits = jax_bits(kj0, kj1, p * 150u + (uint32_t)k);
        float u = __uint_as_float((bits >> 9) | 0x3F800000u) - 1.0f;
        u = fmaxf(u, 1.17549435e-38f);
        const float nlu = -LN2f * LOG2R(u);
        const float g = -LN2f * LOG2R(nlu);
        const float dx = xi0 - x1L[k * 3 + 0];
        const float dy = xi1 - x1L[k * 3 + 1];
        const float dz = xi2 - x1L[k * 3 + 2];
        const float d2 = fmaf(dz, dz, fmaf(dy, dy, dx * dx));
        const float val = fmaf(psiS[k] + nsc * d2, LN2f, g);  // phi_i const over k
        if (val > best || (val == best && k < bestk)) { best = val; bestk = k; }
      }
    }
    #pragma unroll
    for (int off = 1; off < 64; off <<= 1) {
      const float ov = __shfl_xor(best, off);
      const int   ok = __shfl_xor(bestk, off);
      if (ov > best || (ov == best && ok < bestk)) { best = ov; bestk = ok; }
    }
    if (lane == 0) {
      const int j = bestk;
      const float mot = mskS[j];
      const float q0 = x1L[j * 3 + 0], q1 = x1L[j * 3 + 1], q2 = x1L[j * 3 + 2];
      const float omt = 1.f - tb;
      yu[n * 9 + 0] = xi0 * tb + q0 * omt + SIGMAf * epsg[b * 450 + n * 3 + 0];
      yu[n * 9 + 1] = xi1 * tb + q1 * omt + SIGMAf * epsg[b * 450 + n * 3 + 1];
      yu[n * 9 + 2] = xi2 * tb + q2 * omt + SIGMAf * epsg[b * 450 + n * 3 + 2];
      yu[n * 9 + 3] = (xi0 - q0) * mot;
      yu[n * 9 + 4] = (xi1 - q1) * mot;
      yu[n * 9 + 5] = (xi2 - q2) * mot;
      yu[n * 9 + 6] = mot;
    }
  }
  __syncthreads();

  // ---- S2: MLP, lane = sample, hd loop uniform -> scalar W loads ----
  float loss = 0.f;
  if (wid < 3) {
    const int n = wid * 64 + lane;
    if (n < N_) {
      const float y0 = yu[n * 9 + 0], y1 = yu[n * 9 + 1], y2 = yu[n * 9 + 2];
      const float u0 = yu[n * 9 + 3], u1 = yu[n * 9 + 4], u2 = yu[n * 9 + 5];
      const float mot = yu[n * 9 + 6];
      float a0 = 0.f, a1 = 0.f, a2 = 0.f;
      #pragma unroll 4
      for (int hd = 0; hd < 512; ++hd) {
        float z = b1[hd];
        z = fmaf(y0, W1[hd],        z);
        z = fmaf(y1, W1[512 + hd],  z);
        z = fmaf(y2, W1[1024 + hd], z);
        z = fmaf(tb, W1[1536 + hd], z);
        const float zc = fmaf(0.044715f * z, z * z, z);
        const float e2 = EXP2R(-2.3022082062161855f * zc);
        const float ge = z * __builtin_amdgcn_rcpf(1.f + e2);
        a0 = fmaf(ge, W2[hd * 3 + 0], a0);
        a1 = fmaf(ge, W2[hd * 3 + 1], a1);
        a2 = fmaf(ge, W2[hd * 3 + 2], a2);
      }
      const float v0 = (a0 + b2[0]) * mot;
      const float v1 = (a1 + b2[1]) * mot;
      const float v2 = (a2 + b2[2]) * mot;
      const float d0 = v0 - u0, d1 = v1 - u1, d2 = v2 - u2;
      loss = fmaf(d2, d2, fmaf(d1, d1, d0 * d0));
    }
    #pragma unroll
    for (int off = 1; off < 64; off <<= 1) loss += __shfl_xor(loss, off);
    if (lane == 0) red[wid] = loss;
  }
  __syncthreads();
  if (tid == 0) partials[b] = red[0] + red[1] + red[2];
}

__global__ void cfm_reduce_kernel(const float* __restrict__ partials,
                                  float* __restrict__ out) {
  const int tid = threadIdx.x;   // 64 threads
  float s = 0.f;
  #pragma unroll
  for (int q = 0; q < 8; ++q) s += partials[tid + 64 * q];
  #pragma unroll
  for (int off = 1; off < 64; off <<= 1) s += __shfl_xor(s, off);
  if (tid == 0) out[0] = s * (1.0f / 230400.0f);
}

extern "C" void kernel_launch(void* const* d_in, const int* in_sizes, int n_in,
                              void* d_out, int out_size, void* d_ws, size_t ws_size,
                              hipStream_t stream) {
  (void)in_sizes; (void)n_in; (void)out_size; (void)ws_size;
  const float* x    = (const float*)d_in[0];
  const float* mask = (const float*)d_in[1];
  const float* t    = (const float*)d_in[2];
  const float* x0n  = (const float*)d_in[3];
  const float* epsn = (const float*)d_in[4];
  const float* W1   = (const float*)d_in[5];
  const float* b1   = (const float*)d_in[6];
  const float* W2   = (const float*)d_in[7];
  const float* b2   = (const float*)d_in[8];
  float* out = (float*)d_out;

  float* pp       = (float*)d_ws;              // 512 * 152 floats
  float* partials = pp + B_ * PPS;             // 512 floats

  uint32_t ki0, ki1, kj0, kj1, k1r0, k1r1, k2r0, k2r1;
  tf2x32(0u, 42u, 0u, 0u, ki0, ki1);
  tf2x32(0u, 42u, 0u, 1u, kj0, kj1);
  tf2x32(ki0, ki1, 0u, 0u, k1r0, k1r1);
  tf2x32(ki0, ki1, 0u, 1u, k2r0, k2r1);

  cfm_ot_kernel<<<B_, NT, 0, stream>>>(x, x0n, pp);
  cfm_sample_kernel<<<B_, NT, 0, stream>>>(x, mask, t, x0n, epsn, W1, b1, W2, b2,
                                           pp, partials,
                                           kj0, kj1, k1r0, k1r1, k2r0, k2r1);
  cfm_reduce_kernel<<<1, 64, 0, stream>>>(partials, out);
}